// Round 4
// baseline (456.998 us; speedup 1.0000x reference)
//
#include <hip/hip_runtime.h>
#include <hip/hip_fp16.h>
#include <math.h>

// GAT layer: N=50000, E=800000, IN=256, H=4, C=32.
// R4: 8x-replicated denom/cnt accumulators keyed by blockIdx&7 (~XCD id) to
//     kill cross-XCD atomic line ping-pong; one thread/edge in pass A;
//     fp16 edge weights (8B/edge).
// Pipeline:
//   init(denomR,cntR) -> gemm(h_bf) -> node_dots(al,ar)
//   -> edge passA (thread/edge): p4=exp(leaky(al4[dst]+ar4[src]));
//        denomR[rep][src][0..3]+=p; cntR[rep][dst]++
//   -> reduce (fold 8 replicas -> denom, cnt)
//   -> scan1/2/3 (dst-CSR rowptr) -> scatter (elist=src, wlist=half4 p/denom)
//   -> agg: out[n][c] = bias[c] + sum_i bf2f(h_bf[src_i][c]) * half2f(w[i][hh])

#define NH 4
#define CH 32
#define HC 128
#define IND 256
#define NEG_SLOPE 0.2f
#define NREP 8

__device__ __forceinline__ unsigned short f2bf(float f) {
    unsigned int u = __float_as_uint(f);
    unsigned int r = (u + 0x7FFFu + ((u >> 16) & 1u)) >> 16;   // RNE
    return (unsigned short)r;
}
__device__ __forceinline__ float bf2f(unsigned short s) {
    return __uint_as_float(((unsigned int)s) << 16);
}

__global__ __launch_bounds__(256) void k_init(float* __restrict__ denomR,
                                              int* __restrict__ cntR,
                                              int nodeTot, int N) {
    int t = blockIdx.x * 256 + threadIdx.x;
    if (t < NREP * nodeTot) denomR[t] = 0.0f;
    if (t < NREP * N) cntR[t] = 0;
}

// h_bf = bf16(x @ W) : (N x 256) @ (256 x 128), fp32 accumulate.
__global__ __launch_bounds__(256) void k_gemm(const float* __restrict__ x,
                                              const float* __restrict__ W,
                                              unsigned short* __restrict__ h_bf,
                                              int N) {
    __shared__ float xs[64 * 33];
    __shared__ float ws[32 * 128];
    const int tid  = threadIdx.x;
    const int row0 = blockIdx.x * 64;
    const int col4 = (tid & 31) * 4;
    const int rowg = tid >> 5;

    float acc[8][4];
#pragma unroll
    for (int i = 0; i < 8; i++)
#pragma unroll
        for (int j = 0; j < 4; j++) acc[i][j] = 0.0f;

    for (int k0 = 0; k0 < IND; k0 += 32) {
#pragma unroll
        for (int j = 0; j < 2; j++) {
            int lin = (tid + j * 256) * 4;
            int r   = lin >> 5;
            int kk  = lin & 31;
            int row = row0 + r;
            float4 v = make_float4(0.f, 0.f, 0.f, 0.f);
            if (row < N) v = *(const float4*)(x + (size_t)row * IND + k0 + kk);
            xs[r * 33 + kk + 0] = v.x;
            xs[r * 33 + kk + 1] = v.y;
            xs[r * 33 + kk + 2] = v.z;
            xs[r * 33 + kk + 3] = v.w;
        }
#pragma unroll
        for (int j = 0; j < 4; j++) {
            int lin = (tid + j * 256) * 4;
            int kk  = lin >> 7;
            int c   = lin & 127;
            *(float4*)(ws + kk * 128 + c) =
                *(const float4*)(W + (size_t)(k0 + kk) * HC + c);
        }
        __syncthreads();
#pragma unroll
        for (int kk = 0; kk < 32; kk++) {
            float4 wv = *(const float4*)(ws + kk * 128 + col4);
#pragma unroll
            for (int i = 0; i < 8; i++) {
                float xv = xs[(rowg * 8 + i) * 33 + kk];
                acc[i][0] += xv * wv.x;
                acc[i][1] += xv * wv.y;
                acc[i][2] += xv * wv.z;
                acc[i][3] += xv * wv.w;
            }
        }
        __syncthreads();
    }
#pragma unroll
    for (int i = 0; i < 8; i++) {
        int row = row0 + rowg * 8 + i;
        if (row < N) {
            ushort4 o;
            o.x = f2bf(acc[i][0]);
            o.y = f2bf(acc[i][1]);
            o.z = f2bf(acc[i][2]);
            o.w = f2bf(acc[i][3]);
            *(ushort4*)(h_bf + (size_t)row * HC + col4) = o;
        }
    }
}

__global__ __launch_bounds__(256) void k_node_dots(const unsigned short* __restrict__ h_bf,
                                                   const float* __restrict__ att,
                                                   float* __restrict__ al,
                                                   float* __restrict__ ar, int N) {
    int t = blockIdx.x * 256 + threadIdx.x;
    if (t >= N * NH) return;
    int n = t >> 2, hh = t & 3;
    const unsigned short* hp = h_bf + (size_t)n * HC + hh * CH;
    const float* wl = att + hh * (2 * CH);
    const float* wr = wl + CH;
    float sl = 0.f, sr = 0.f;
#pragma unroll
    for (int c = 0; c < CH; c += 4) {
        ushort4 hv = *(const ushort4*)(hp + c);
        float4  lv = *(const float4*)(wl + c);
        float4  rv = *(const float4*)(wr + c);
        float h0 = bf2f(hv.x), h1 = bf2f(hv.y), h2 = bf2f(hv.z), h3 = bf2f(hv.w);
        sl += h0 * lv.x + h1 * lv.y + h2 * lv.z + h3 * lv.w;
        sr += h0 * rv.x + h1 * rv.y + h2 * rv.z + h3 * rv.w;
    }
    al[t] = sl;
    ar[t] = sr;
}

// pass A, one thread per edge: p4 = exp(leaky(al4[dst]+ar4[src]));
// denomR[rep][src*4+h] += p[h]; cntR[rep][dst] += 1.
__global__ __launch_bounds__(256) void k_edge_pA(const int* __restrict__ ei,
                                                 const float* __restrict__ al,
                                                 const float* __restrict__ ar,
                                                 float* __restrict__ denomR,
                                                 int* __restrict__ cntR,
                                                 int E, int NE, int nodeTot, int N) {
    int t = blockIdx.x * 256 + threadIdx.x;
    if (t >= NE) return;
    int src, dst;
    if (t < E) { src = ei[t]; dst = ei[E + t]; }
    else       { src = dst = t - E; }
    float4 av = *(const float4*)(al + dst * NH);
    float4 rv = *(const float4*)(ar + src * NH);
    float a0 = av.x + rv.x, a1 = av.y + rv.y, a2 = av.z + rv.z, a3 = av.w + rv.w;
    a0 = (a0 > 0.f) ? a0 : NEG_SLOPE * a0;
    a1 = (a1 > 0.f) ? a1 : NEG_SLOPE * a1;
    a2 = (a2 > 0.f) ? a2 : NEG_SLOPE * a2;
    a3 = (a3 > 0.f) ? a3 : NEG_SLOPE * a3;
    int rep = blockIdx.x & (NREP - 1);
    float* d = denomR + (size_t)rep * nodeTot + src * NH;
    atomicAdd(d + 0, __expf(a0));
    atomicAdd(d + 1, __expf(a1));
    atomicAdd(d + 2, __expf(a2));
    atomicAdd(d + 3, __expf(a3));
    atomicAdd(&cntR[rep * N + dst], 1);
}

// fold replicas: denom[t] = sum_r denomR[r][t]; cnt[n] = sum_r cntR[r][n]
__global__ __launch_bounds__(256) void k_reduce(const float* __restrict__ denomR,
                                                const int* __restrict__ cntR,
                                                float* __restrict__ denom,
                                                int* __restrict__ cnt,
                                                int nodeTot, int N) {
    int t = blockIdx.x * 256 + threadIdx.x;
    if (t < nodeTot) {
        float s = 0.f;
#pragma unroll
        for (int r = 0; r < NREP; r++) s += denomR[(size_t)r * nodeTot + t];
        denom[t] = s;
    }
    if (t < N) {
        int c = 0;
#pragma unroll
        for (int r = 0; r < NREP; r++) c += cntR[r * N + t];
        cnt[t] = c;
    }
}

// ---- 3-kernel exclusive scan of cnt[N]
__global__ __launch_bounds__(256) void k_scan1(const int* __restrict__ cnt,
                                               int* __restrict__ excl,
                                               int* __restrict__ bsums, int N) {
    __shared__ int lds[256];
    int tid  = threadIdx.x;
    int base = blockIdx.x * 1024 + tid * 4;
    int v0 = (base + 0 < N) ? cnt[base + 0] : 0;
    int v1 = (base + 1 < N) ? cnt[base + 1] : 0;
    int v2 = (base + 2 < N) ? cnt[base + 2] : 0;
    int v3 = (base + 3 < N) ? cnt[base + 3] : 0;
    int e1 = v0, e2 = v0 + v1, e3 = v0 + v1 + v2;
    int tot = e3 + v3;
    lds[tid] = tot;
    __syncthreads();
    for (int off = 1; off < 256; off <<= 1) {
        int t = (tid >= off) ? lds[tid - off] : 0;
        __syncthreads();
        lds[tid] += t;
        __syncthreads();
    }
    int exoff = lds[tid] - tot;
    if (base + 0 < N) excl[base + 0] = exoff;
    if (base + 1 < N) excl[base + 1] = exoff + e1;
    if (base + 2 < N) excl[base + 2] = exoff + e2;
    if (base + 3 < N) excl[base + 3] = exoff + e3;
    if (tid == 255) bsums[blockIdx.x] = lds[255];
}

__global__ __launch_bounds__(256) void k_scan2(int* __restrict__ bsums, int nb) {
    __shared__ int lds[256];
    int tid = threadIdx.x;
    int v = (tid < nb) ? bsums[tid] : 0;
    lds[tid] = v;
    __syncthreads();
    for (int off = 1; off < 256; off <<= 1) {
        int t = (tid >= off) ? lds[tid - off] : 0;
        __syncthreads();
        lds[tid] += t;
        __syncthreads();
    }
    if (tid < nb) bsums[tid] = lds[tid] - v;
}

__global__ __launch_bounds__(256) void k_scan3(int* __restrict__ rowptr,
                                               int* __restrict__ woff,
                                               const int* __restrict__ bsums,
                                               int N, int NE) {
    int t = blockIdx.x * 256 + threadIdx.x;
    if (t < N) {
        int v = rowptr[t] + bsums[t >> 10];
        rowptr[t] = v;
        woff[t]   = v;
    }
    if (t == 0) rowptr[N] = NE;
}

// scatter: recompute p, divide by denom[src], store src + half4 weights.
__global__ __launch_bounds__(256) void k_scatter(const int* __restrict__ ei,
                                                 const float* __restrict__ al,
                                                 const float* __restrict__ ar,
                                                 const float* __restrict__ denom,
                                                 int* __restrict__ woff,
                                                 int* __restrict__ elist,
                                                 ushort4* __restrict__ wlist,
                                                 int E, int NE) {
    int t = blockIdx.x * 256 + threadIdx.x;
    if (t >= NE) return;
    int src, dst;
    if (t < E) { src = ei[t]; dst = ei[E + t]; }
    else       { src = dst = t - E; }
    float4 av = *(const float4*)(al + dst * NH);
    float4 rv = *(const float4*)(ar + src * NH);
    float4 dv = *(const float4*)(denom + src * NH);
    float a0 = av.x + rv.x, a1 = av.y + rv.y, a2 = av.z + rv.z, a3 = av.w + rv.w;
    a0 = (a0 > 0.f) ? a0 : NEG_SLOPE * a0;
    a1 = (a1 > 0.f) ? a1 : NEG_SLOPE * a1;
    a2 = (a2 > 0.f) ? a2 : NEG_SLOPE * a2;
    a3 = (a3 > 0.f) ? a3 : NEG_SLOPE * a3;
    ushort4 w;
    w.x = __half_as_ushort(__float2half(__expf(a0) / (dv.x + 1e-16f)));
    w.y = __half_as_ushort(__float2half(__expf(a1) / (dv.y + 1e-16f)));
    w.z = __half_as_ushort(__float2half(__expf(a2) / (dv.z + 1e-16f)));
    w.w = __half_as_ushort(__float2half(__expf(a3) / (dv.w + 1e-16f)));
    int pos = atomicAdd(&woff[dst], 1);
    elist[pos] = src;
    wlist[pos] = w;
}

// agg: 4 nodes/block, 64 threads/node, 2 channels/thread (ushort2 loads).
__global__ __launch_bounds__(256) void k_agg(const int* __restrict__ rowptr,
                                             const int* __restrict__ elist,
                                             const unsigned short* __restrict__ wlist,
                                             const unsigned short* __restrict__ h_bf,
                                             const float* __restrict__ bias,
                                             float* __restrict__ out, int N) {
    int n = blockIdx.x * 4 + (threadIdx.x >> 6);
    if (n >= N) return;
    int lane = threadIdx.x & 63;
    int c    = lane * 2;
    int hh   = lane >> 4;
    int beg = rowptr[n], end = rowptr[n + 1];
    float a0 = bias[c], a1 = bias[c + 1];
    float b0 = 0.f, b1 = 0.f;
    int i = beg;
    for (; i + 2 <= end; i += 2) {
        int s0 = elist[i];
        int s1 = elist[i + 1];
        float w0 = __half2float(__ushort_as_half(wlist[i * 4 + hh]));
        float w1 = __half2float(__ushort_as_half(wlist[(i + 1) * 4 + hh]));
        ushort2 u0 = *(const ushort2*)(h_bf + (size_t)s0 * HC + c);
        ushort2 u1 = *(const ushort2*)(h_bf + (size_t)s1 * HC + c);
        a0 += bf2f(u0.x) * w0;
        a1 += bf2f(u0.y) * w0;
        b0 += bf2f(u1.x) * w1;
        b1 += bf2f(u1.y) * w1;
    }
    if (i < end) {
        int s0 = elist[i];
        float w0 = __half2float(__ushort_as_half(wlist[i * 4 + hh]));
        ushort2 u0 = *(const ushort2*)(h_bf + (size_t)s0 * HC + c);
        a0 += bf2f(u0.x) * w0;
        a1 += bf2f(u0.y) * w0;
    }
    *(float2*)(out + (size_t)n * HC + c) = make_float2(a0 + b0, a1 + b1);
}

extern "C" void kernel_launch(void* const* d_in, const int* in_sizes, int n_in,
                              void* d_out, int out_size, void* d_ws, size_t ws_size,
                              hipStream_t stream) {
    const float* x    = (const float*)d_in[0];
    const float* W    = (const float*)d_in[1];
    const float* att  = (const float*)d_in[2];
    const float* bias = (const float*)d_in[3];
    const int*   ei   = (const int*)d_in[4];

    const int N  = in_sizes[0] / IND;     // 50000
    const int E  = in_sizes[4] / 2;       // 800000
    const int NE = E + N;
    float* out = (float*)d_out;
    const int nodeTot = N * NH;

    // ws layout (16B alignment preserved through the float4-accessed arrays)
    unsigned short* h_bf = (unsigned short*)d_ws;            // N*128 u16 = 12.8MB
    ushort4* wlist = (ushort4*)(h_bf + (size_t)N * HC);      // NE*8B = 6.8MB
    float*  al     = (float*)(wlist + NE);                   // N*4 f32
    float*  ar     = al + (size_t)nodeTot;                   // N*4
    float*  denom  = ar + (size_t)nodeTot;                   // N*4
    float*  denomR = denom + (size_t)nodeTot;                // 8*N*4 = 6.4MB
    int*    cntR   = (int*)(denomR + (size_t)NREP * nodeTot);// 8*N = 1.6MB
    int*    cnt    = cntR + NREP * N;                        // N
    int*    rowptr = cnt + N;                                // N+1 (+pad)
    int*    woff   = rowptr + (N + 2);                       // N
    int*    bsums  = woff + N;                               // 256
    int*    elist  = bsums + 256;                            // NE

    const int nb1 = (N + 1023) / 1024;

    k_init<<<(NREP * nodeTot + 255) / 256, 256, 0, stream>>>(denomR, cntR, nodeTot, N);
    k_gemm<<<(N + 63) / 64, 256, 0, stream>>>(x, W, h_bf, N);
    k_node_dots<<<(nodeTot + 255) / 256, 256, 0, stream>>>(h_bf, att, al, ar, N);
    k_edge_pA<<<(NE + 255) / 256, 256, 0, stream>>>(ei, al, ar, denomR, cntR, E, NE, nodeTot, N);
    k_reduce<<<(nodeTot + 255) / 256, 256, 0, stream>>>(denomR, cntR, denom, cnt, nodeTot, N);
    k_scan1<<<nb1, 256, 0, stream>>>(cnt, rowptr, bsums, N);
    k_scan2<<<1, 256, 0, stream>>>(bsums, nb1);
    k_scan3<<<(N + 255) / 256, 256, 0, stream>>>(rowptr, woff, bsums, N, NE);
    k_scatter<<<(NE + 255) / 256, 256, 0, stream>>>(ei, al, ar, denom, woff, elist, wlist, E, NE);
    k_agg<<<(N + 3) / 4, 256, 0, stream>>>(rowptr, elist, (const unsigned short*)wlist, h_bf, bias, out, N);
}

// Round 5
// 434.243 us; speedup vs baseline: 1.0524x; 1.0524x over previous
//
#include <hip/hip_runtime.h>
#include <math.h>

// GAT layer: N=50000, E=800000, IN=256, H=4, C=32.
// R5: NO float atomics anywhere. One combined scan builds BOTH CSRs:
//   cnt[0..N)   = out-degree (src),  cnt[N..2N) = in-degree (dst);
//   sum(cnt_src)=NE, so one exclusive scan over 2N gives
//   rowptr[n]     = src-CSR offsets into adj[0..NE)
//   rowptr[N+n]   = dst-CSR offsets into adj[NE..2NE)
// denom = gather-reduce over src-CSR (stores reciprocal).
// agg   = gather-reduce over dst-CSR, recomputing w = exp(leaky(.))*rdenom
//         inline (no wlist materialization).
// Pipeline (10 dispatches):
//   init -> gemm(h_bf) -> node_dots -> count2 -> scan1/2/3 -> scatter2
//   -> denom -> agg

#define NH 4
#define CH 32
#define HC 128
#define IND 256
#define NEG_SLOPE 0.2f

__device__ __forceinline__ unsigned short f2bf(float f) {
    unsigned int u = __float_as_uint(f);
    unsigned int r = (u + 0x7FFFu + ((u >> 16) & 1u)) >> 16;   // RNE
    return (unsigned short)r;
}
__device__ __forceinline__ float bf2f(unsigned short s) {
    return __uint_as_float(((unsigned int)s) << 16);
}

__global__ __launch_bounds__(256) void k_init(int* __restrict__ cnt, int M) {
    int t = blockIdx.x * 256 + threadIdx.x;
    if (t < M) cnt[t] = 0;
}

// h_bf = bf16(x @ W) : (N x 256) @ (256 x 128), fp32 accumulate.
__global__ __launch_bounds__(256) void k_gemm(const float* __restrict__ x,
                                              const float* __restrict__ W,
                                              unsigned short* __restrict__ h_bf,
                                              int N) {
    __shared__ float xs[64 * 33];
    __shared__ float ws[32 * 128];
    const int tid  = threadIdx.x;
    const int row0 = blockIdx.x * 64;
    const int col4 = (tid & 31) * 4;
    const int rowg = tid >> 5;

    float acc[8][4];
#pragma unroll
    for (int i = 0; i < 8; i++)
#pragma unroll
        for (int j = 0; j < 4; j++) acc[i][j] = 0.0f;

    for (int k0 = 0; k0 < IND; k0 += 32) {
#pragma unroll
        for (int j = 0; j < 2; j++) {
            int lin = (tid + j * 256) * 4;
            int r   = lin >> 5;
            int kk  = lin & 31;
            int row = row0 + r;
            float4 v = make_float4(0.f, 0.f, 0.f, 0.f);
            if (row < N) v = *(const float4*)(x + (size_t)row * IND + k0 + kk);
            xs[r * 33 + kk + 0] = v.x;
            xs[r * 33 + kk + 1] = v.y;
            xs[r * 33 + kk + 2] = v.z;
            xs[r * 33 + kk + 3] = v.w;
        }
#pragma unroll
        for (int j = 0; j < 4; j++) {
            int lin = (tid + j * 256) * 4;
            int kk  = lin >> 7;
            int c   = lin & 127;
            *(float4*)(ws + kk * 128 + c) =
                *(const float4*)(W + (size_t)(k0 + kk) * HC + c);
        }
        __syncthreads();
#pragma unroll
        for (int kk = 0; kk < 32; kk++) {
            float4 wv = *(const float4*)(ws + kk * 128 + col4);
#pragma unroll
            for (int i = 0; i < 8; i++) {
                float xv = xs[(rowg * 8 + i) * 33 + kk];
                acc[i][0] += xv * wv.x;
                acc[i][1] += xv * wv.y;
                acc[i][2] += xv * wv.z;
                acc[i][3] += xv * wv.w;
            }
        }
        __syncthreads();
    }
#pragma unroll
    for (int i = 0; i < 8; i++) {
        int row = row0 + rowg * 8 + i;
        if (row < N) {
            ushort4 o;
            o.x = f2bf(acc[i][0]);
            o.y = f2bf(acc[i][1]);
            o.z = f2bf(acc[i][2]);
            o.w = f2bf(acc[i][3]);
            *(ushort4*)(h_bf + (size_t)row * HC + col4) = o;
        }
    }
}

__global__ __launch_bounds__(256) void k_node_dots(const unsigned short* __restrict__ h_bf,
                                                   const float* __restrict__ att,
                                                   float* __restrict__ al,
                                                   float* __restrict__ ar, int N) {
    int t = blockIdx.x * 256 + threadIdx.x;
    if (t >= N * NH) return;
    int n = t >> 2, hh = t & 3;
    const unsigned short* hp = h_bf + (size_t)n * HC + hh * CH;
    const float* wl = att + hh * (2 * CH);
    const float* wr = wl + CH;
    float sl = 0.f, sr = 0.f;
#pragma unroll
    for (int c = 0; c < CH; c += 4) {
        ushort4 hv = *(const ushort4*)(hp + c);
        float4  lv = *(const float4*)(wl + c);
        float4  rv = *(const float4*)(wr + c);
        float h0 = bf2f(hv.x), h1 = bf2f(hv.y), h2 = bf2f(hv.z), h3 = bf2f(hv.w);
        sl += h0 * lv.x + h1 * lv.y + h2 * lv.z + h3 * lv.w;
        sr += h0 * rv.x + h1 * rv.y + h2 * rv.z + h3 * rv.w;
    }
    al[t] = sl;
    ar[t] = sr;
}

// count both degrees: cnt[src]++ (out-deg), cnt[N+dst]++ (in-deg). Dense int
// histograms: 16 nodes/cache-line, lines stay L2-resident.
__global__ __launch_bounds__(256) void k_count2(const int* __restrict__ ei,
                                                int* __restrict__ cnt,
                                                int E, int NE, int N) {
    int t = blockIdx.x * 256 + threadIdx.x;
    if (t >= NE) return;
    int src, dst;
    if (t < E) { src = ei[t]; dst = ei[E + t]; }
    else       { src = dst = t - E; }
    atomicAdd(&cnt[src], 1);
    atomicAdd(&cnt[N + dst], 1);
}

// ---- 3-kernel exclusive scan of cnt[M], M = 2N
__global__ __launch_bounds__(256) void k_scan1(const int* __restrict__ cnt,
                                               int* __restrict__ excl,
                                               int* __restrict__ bsums, int M) {
    __shared__ int lds[256];
    int tid  = threadIdx.x;
    int base = blockIdx.x * 1024 + tid * 4;
    int v0 = (base + 0 < M) ? cnt[base + 0] : 0;
    int v1 = (base + 1 < M) ? cnt[base + 1] : 0;
    int v2 = (base + 2 < M) ? cnt[base + 2] : 0;
    int v3 = (base + 3 < M) ? cnt[base + 3] : 0;
    int e1 = v0, e2 = v0 + v1, e3 = v0 + v1 + v2;
    int tot = e3 + v3;
    lds[tid] = tot;
    __syncthreads();
    for (int off = 1; off < 256; off <<= 1) {
        int t = (tid >= off) ? lds[tid - off] : 0;
        __syncthreads();
        lds[tid] += t;
        __syncthreads();
    }
    int exoff = lds[tid] - tot;
    if (base + 0 < M) excl[base + 0] = exoff;
    if (base + 1 < M) excl[base + 1] = exoff + e1;
    if (base + 2 < M) excl[base + 2] = exoff + e2;
    if (base + 3 < M) excl[base + 3] = exoff + e3;
    if (tid == 255) bsums[blockIdx.x] = lds[255];
}

__global__ __launch_bounds__(256) void k_scan2(int* __restrict__ bsums, int nb) {
    __shared__ int lds[256];
    int tid = threadIdx.x;
    int v = (tid < nb) ? bsums[tid] : 0;
    lds[tid] = v;
    __syncthreads();
    for (int off = 1; off < 256; off <<= 1) {
        int t = (tid >= off) ? lds[tid - off] : 0;
        __syncthreads();
        lds[tid] += t;
        __syncthreads();
    }
    if (tid < nb) bsums[tid] = lds[tid] - v;
}

__global__ __launch_bounds__(256) void k_scan3(int* __restrict__ rowptr,
                                               int* __restrict__ woff,
                                               const int* __restrict__ bsums,
                                               int M, int total) {
    int t = blockIdx.x * 256 + threadIdx.x;
    if (t < M) {
        int v = rowptr[t] + bsums[t >> 10];
        rowptr[t] = v;
        woff[t]   = v;
    }
    if (t == 0) rowptr[M] = total;
}

// one pass fills BOTH adjacency halves:
//   adj[woff[src]++]   = dst   (src-CSR half, [0,NE))
//   adj[woff[N+dst]++] = src   (dst-CSR half, [NE,2NE))
__global__ __launch_bounds__(256) void k_scatter2(const int* __restrict__ ei,
                                                  int* __restrict__ woff,
                                                  int* __restrict__ adj,
                                                  int E, int NE, int N) {
    int t = blockIdx.x * 256 + threadIdx.x;
    if (t >= NE) return;
    int src, dst;
    if (t < E) { src = ei[t]; dst = ei[E + t]; }
    else       { src = dst = t - E; }
    int ps = atomicAdd(&woff[src], 1);
    adj[ps] = dst;
    int pd = atomicAdd(&woff[N + dst], 1);
    adj[pd] = src;
}

// rdenom[n][h] = 1 / (sum over out-edges exp(leaky(al[dst]+ar[n])) + 1e-16)
// one thread per node, float4 al gathers (L2-resident 800KB).
__global__ __launch_bounds__(256) void k_denom(const int* __restrict__ rowptr,
                                               const int* __restrict__ adj,
                                               const float* __restrict__ al,
                                               const float* __restrict__ ar,
                                               float* __restrict__ rdenom, int N) {
    int n = blockIdx.x * 256 + threadIdx.x;
    if (n >= N) return;
    int beg = rowptr[n], end = rowptr[n + 1];
    float4 arv = *(const float4*)(ar + n * NH);
    float s0 = 0.f, s1 = 0.f, s2 = 0.f, s3 = 0.f;
    for (int i = beg; i < end; i++) {
        int d = adj[i];
        float4 av = *(const float4*)(al + d * NH);
        float a0 = av.x + arv.x, a1 = av.y + arv.y;
        float a2 = av.z + arv.z, a3 = av.w + arv.w;
        a0 = (a0 > 0.f) ? a0 : NEG_SLOPE * a0;
        a1 = (a1 > 0.f) ? a1 : NEG_SLOPE * a1;
        a2 = (a2 > 0.f) ? a2 : NEG_SLOPE * a2;
        a3 = (a3 > 0.f) ? a3 : NEG_SLOPE * a3;
        s0 += __expf(a0); s1 += __expf(a1);
        s2 += __expf(a2); s3 += __expf(a3);
    }
    float4 r;
    r.x = 1.0f / (s0 + 1e-16f);
    r.y = 1.0f / (s1 + 1e-16f);
    r.z = 1.0f / (s2 + 1e-16f);
    r.w = 1.0f / (s3 + 1e-16f);
    *(float4*)(rdenom + n * NH) = r;
}

// agg over dst-CSR: out[n][c] = bias[c] + sum_i bf2f(h_bf[s_i][c]) * w_i,
// w_i = exp(leaky(al[n][hh]+ar[s_i][hh])) * rdenom[s_i][hh], recomputed inline.
// 4 nodes/block, 64 threads/node, 2 channels/thread.
__global__ __launch_bounds__(256) void k_agg(const int* __restrict__ rowptr,
                                             const int* __restrict__ adj,
                                             const float* __restrict__ al,
                                             const float* __restrict__ ar,
                                             const float* __restrict__ rdenom,
                                             const unsigned short* __restrict__ h_bf,
                                             const float* __restrict__ bias,
                                             float* __restrict__ out, int N) {
    int n = blockIdx.x * 4 + (threadIdx.x >> 6);
    if (n >= N) return;
    int lane = threadIdx.x & 63;
    int c    = lane * 2;
    int hh   = lane >> 4;
    int beg = rowptr[N + n], end = rowptr[N + n + 1];   // dst-CSR half
    float alv = al[n * NH + hh];
    float a0 = bias[c], a1 = bias[c + 1];
    float b0 = 0.f, b1 = 0.f;
    int i = beg;
    for (; i + 2 <= end; i += 2) {
        int s0 = adj[i];
        int s1 = adj[i + 1];
        float e0 = alv + ar[s0 * NH + hh];
        float e1 = alv + ar[s1 * NH + hh];
        e0 = (e0 > 0.f) ? e0 : NEG_SLOPE * e0;
        e1 = (e1 > 0.f) ? e1 : NEG_SLOPE * e1;
        float w0 = __expf(e0) * rdenom[s0 * NH + hh];
        float w1 = __expf(e1) * rdenom[s1 * NH + hh];
        ushort2 u0 = *(const ushort2*)(h_bf + (size_t)s0 * HC + c);
        ushort2 u1 = *(const ushort2*)(h_bf + (size_t)s1 * HC + c);
        a0 += bf2f(u0.x) * w0;
        a1 += bf2f(u0.y) * w0;
        b0 += bf2f(u1.x) * w1;
        b1 += bf2f(u1.y) * w1;
    }
    if (i < end) {
        int s0 = adj[i];
        float e0 = alv + ar[s0 * NH + hh];
        e0 = (e0 > 0.f) ? e0 : NEG_SLOPE * e0;
        float w0 = __expf(e0) * rdenom[s0 * NH + hh];
        ushort2 u0 = *(const ushort2*)(h_bf + (size_t)s0 * HC + c);
        a0 += bf2f(u0.x) * w0;
        a1 += bf2f(u0.y) * w0;
    }
    *(float2*)(out + (size_t)n * HC + c) = make_float2(a0 + b0, a1 + b1);
}

extern "C" void kernel_launch(void* const* d_in, const int* in_sizes, int n_in,
                              void* d_out, int out_size, void* d_ws, size_t ws_size,
                              hipStream_t stream) {
    const float* x    = (const float*)d_in[0];
    const float* W    = (const float*)d_in[1];
    const float* att  = (const float*)d_in[2];
    const float* bias = (const float*)d_in[3];
    const int*   ei   = (const int*)d_in[4];

    const int N  = in_sizes[0] / IND;     // 50000
    const int E  = in_sizes[4] / 2;       // 800000
    const int NE = E + N;
    const int M  = 2 * N;                 // combined count length
    float* out = (float*)d_out;
    const int nodeTot = N * NH;

    // ws layout (16B-aligned chunks)
    unsigned short* h_bf = (unsigned short*)d_ws;         // N*128 u16 = 12.8MB
    float* al     = (float*)(h_bf + (size_t)N * HC);      // N*4 f32  (16B-mult)
    float* ar     = al + nodeTot;                         // N*4
    float* rdenom = ar + nodeTot;                         // N*4
    int*   cnt    = (int*)(rdenom + nodeTot);             // 2N
    int*   rowptr = cnt + M;                              // 2N+2
    int*   woff   = rowptr + (M + 2);                     // 2N
    int*   bsums  = woff + M;                             // 256
    int*   adj    = bsums + 256;                          // 2*NE = 6.8MB

    const int nb1 = (M + 1023) / 1024;   // 98 blocks <= 256

    k_init<<<(M + 255) / 256, 256, 0, stream>>>(cnt, M);
    k_gemm<<<(N + 63) / 64, 256, 0, stream>>>(x, W, h_bf, N);
    k_node_dots<<<(nodeTot + 255) / 256, 256, 0, stream>>>(h_bf, att, al, ar, N);
    k_count2<<<(NE + 255) / 256, 256, 0, stream>>>(ei, cnt, E, NE, N);
    k_scan1<<<nb1, 256, 0, stream>>>(cnt, rowptr, bsums, M);
    k_scan2<<<1, 256, 0, stream>>>(bsums, nb1);
    k_scan3<<<(M + 255) / 256, 256, 0, stream>>>(rowptr, woff, bsums, M, 2 * NE);
    k_scatter2<<<(NE + 255) / 256, 256, 0, stream>>>(ei, woff, adj, E, NE, N);
    k_denom<<<(N + 255) / 256, 256, 0, stream>>>(rowptr, adj, al, ar, rdenom, N);
    k_agg<<<(N + 3) / 4, 256, 0, stream>>>(rowptr, adj, al, ar, rdenom, h_bf, bias, out, N);
}

// Round 6
// 298.591 us; speedup vs baseline: 1.5305x; 1.4543x over previous
//
#include <hip/hip_runtime.h>
#include <math.h>

// GAT layer: N=50000, E=800000, IN=256, H=4, C=32.
// R6: two-level bucketed CSR build. All random writes are confined to
// block-private regions (one block = one XCD) to kill the cross-XCD L2
// byte-mask writeback amplification measured in R5 (scatter2: 107MB WRITE).
//   k_hist     : coarse (1024-node) bucket histograms, LDS-staged
//   k_scanC    : serial scan -> coarse bases + cursors
//   k_scatterC : 4096-edge chunks, LDS-binned, full-line appends to streams
//   k_rebin    : block per coarse bucket -> node-level CSR (u16 adj) + rowptr
//   k_denom    : gather over src-CSR -> rdenom (reciprocal softmax denom)
//   k_agg      : gather over dst-CSR, w recomputed inline, bias fused

#define NH 4
#define CH 32
#define HC 128
#define IND 256
#define NEG_SLOPE 0.2f
#define CSH 10          // coarse bucket = 1024 nodes
#define NCB_MAX 64
#define CHUNK 4096

__device__ __forceinline__ unsigned short f2bf(float f) {
    unsigned int u = __float_as_uint(f);
    unsigned int r = (u + 0x7FFFu + ((u >> 16) & 1u)) >> 16;   // RNE
    return (unsigned short)r;
}
__device__ __forceinline__ float bf2f(unsigned short s) {
    return __uint_as_float(((unsigned int)s) << 16);
}

__global__ __launch_bounds__(256) void k_init0(int* __restrict__ histS,
                                               int* __restrict__ histD, int ncb) {
    int t = threadIdx.x;
    if (t < ncb) { histS[t] = 0; histD[t] = 0; }
}

// h_bf = bf16(x @ W) : (N x 256) @ (256 x 128), fp32 accumulate.
__global__ __launch_bounds__(256) void k_gemm(const float* __restrict__ x,
                                              const float* __restrict__ W,
                                              unsigned short* __restrict__ h_bf,
                                              int N) {
    __shared__ float xs[64 * 33];
    __shared__ float ws[32 * 128];
    const int tid  = threadIdx.x;
    const int row0 = blockIdx.x * 64;
    const int col4 = (tid & 31) * 4;
    const int rowg = tid >> 5;

    float acc[8][4];
#pragma unroll
    for (int i = 0; i < 8; i++)
#pragma unroll
        for (int j = 0; j < 4; j++) acc[i][j] = 0.0f;

    for (int k0 = 0; k0 < IND; k0 += 32) {
#pragma unroll
        for (int j = 0; j < 2; j++) {
            int lin = (tid + j * 256) * 4;
            int r   = lin >> 5;
            int kk  = lin & 31;
            int row = row0 + r;
            float4 v = make_float4(0.f, 0.f, 0.f, 0.f);
            if (row < N) v = *(const float4*)(x + (size_t)row * IND + k0 + kk);
            xs[r * 33 + kk + 0] = v.x;
            xs[r * 33 + kk + 1] = v.y;
            xs[r * 33 + kk + 2] = v.z;
            xs[r * 33 + kk + 3] = v.w;
        }
#pragma unroll
        for (int j = 0; j < 4; j++) {
            int lin = (tid + j * 256) * 4;
            int kk  = lin >> 7;
            int c   = lin & 127;
            *(float4*)(ws + kk * 128 + c) =
                *(const float4*)(W + (size_t)(k0 + kk) * HC + c);
        }
        __syncthreads();
#pragma unroll
        for (int kk = 0; kk < 32; kk++) {
            float4 wv = *(const float4*)(ws + kk * 128 + col4);
#pragma unroll
            for (int i = 0; i < 8; i++) {
                float xv = xs[(rowg * 8 + i) * 33 + kk];
                acc[i][0] += xv * wv.x;
                acc[i][1] += xv * wv.y;
                acc[i][2] += xv * wv.z;
                acc[i][3] += xv * wv.w;
            }
        }
        __syncthreads();
    }
#pragma unroll
    for (int i = 0; i < 8; i++) {
        int row = row0 + rowg * 8 + i;
        if (row < N) {
            ushort4 o;
            o.x = f2bf(acc[i][0]);
            o.y = f2bf(acc[i][1]);
            o.z = f2bf(acc[i][2]);
            o.w = f2bf(acc[i][3]);
            *(ushort4*)(h_bf + (size_t)row * HC + col4) = o;
        }
    }
}

__global__ __launch_bounds__(256) void k_node_dots(const unsigned short* __restrict__ h_bf,
                                                   const float* __restrict__ att,
                                                   float* __restrict__ al,
                                                   float* __restrict__ ar, int N) {
    int t = blockIdx.x * 256 + threadIdx.x;
    if (t >= N * NH) return;
    int n = t >> 2, hh = t & 3;
    const unsigned short* hp = h_bf + (size_t)n * HC + hh * CH;
    const float* wl = att + hh * (2 * CH);
    const float* wr = wl + CH;
    float sl = 0.f, sr = 0.f;
#pragma unroll
    for (int c = 0; c < CH; c += 4) {
        ushort4 hv = *(const ushort4*)(hp + c);
        float4  lv = *(const float4*)(wl + c);
        float4  rv = *(const float4*)(wr + c);
        float h0 = bf2f(hv.x), h1 = bf2f(hv.y), h2 = bf2f(hv.z), h3 = bf2f(hv.w);
        sl += h0 * lv.x + h1 * lv.y + h2 * lv.z + h3 * lv.w;
        sr += h0 * rv.x + h1 * rv.y + h2 * rv.z + h3 * rv.w;
    }
    al[t] = sl;
    ar[t] = sr;
}

// coarse histograms, LDS-staged (few global atomics).
__global__ __launch_bounds__(256) void k_hist(const int* __restrict__ ei,
                                              int* __restrict__ histS,
                                              int* __restrict__ histD,
                                              int E, int NE, int ncb) {
    __shared__ int hs[NCB_MAX], hd[NCB_MAX];
    for (int i = threadIdx.x; i < NCB_MAX; i += 256) { hs[i] = 0; hd[i] = 0; }
    __syncthreads();
    for (int t = blockIdx.x * 256 + threadIdx.x; t < NE; t += gridDim.x * 256) {
        int src, dst;
        if (t < E) { src = ei[t]; dst = ei[E + t]; }
        else       { src = dst = t - E; }
        atomicAdd(&hs[src >> CSH], 1);
        atomicAdd(&hd[dst >> CSH], 1);
    }
    __syncthreads();
    for (int i = threadIdx.x; i < ncb; i += 256) {
        if (hs[i]) atomicAdd(&histS[i], hs[i]);
        if (hd[i]) atomicAdd(&histD[i], hd[i]);
    }
}

// serial exclusive scan over ncb coarse buckets, both sides; init cursors.
__global__ __launch_bounds__(64) void k_scanC(const int* __restrict__ histS,
                                              const int* __restrict__ histD,
                                              int* __restrict__ baseS,
                                              int* __restrict__ baseD,
                                              int* __restrict__ curS,
                                              int* __restrict__ curD,
                                              int* __restrict__ rowptrS,
                                              int* __restrict__ rowptrD,
                                              int ncb, int NE, int N) {
    if (threadIdx.x == 0) {
        int s = 0;
        for (int i = 0; i < ncb; i++) { baseS[i] = s; curS[i] = s; s += histS[i]; }
        baseS[ncb] = s;
        int d = 0;
        for (int i = 0; i < ncb; i++) { baseD[i] = d; curD[i] = d; d += histD[i]; }
        baseD[ncb] = d;
        rowptrS[N] = NE;
        rowptrD[N] = NE;
    }
}

// chunked scatter into coarse streams: LDS-binned, appended in long runs so
// every record line is written (almost always) by one block.
__global__ __launch_bounds__(256) void k_scatterC(const int* __restrict__ ei,
                                                  int* __restrict__ gcurS,
                                                  int* __restrict__ gcurD,
                                                  unsigned int* __restrict__ recS,
                                                  unsigned int* __restrict__ recD,
                                                  int E, int NE, int ncb) {
    __shared__ unsigned int srt[CHUNK];          // 16 KB
    __shared__ int cnt[NCB_MAX], off[NCB_MAX], cur[NCB_MAX], gpos[NCB_MAX];
    const int tid = threadIdx.x;
    const int t0  = blockIdx.x * CHUNK;
    const int m   = min(CHUNK, NE - t0);

    unsigned int myrec[CHUNK / 256];
    int nmy = 0;
    for (int i = tid; i < m; i += 256) {
        int t = t0 + i;
        int src, dst;
        if (t < E) { src = ei[t]; dst = ei[E + t]; }
        else       { src = dst = t - E; }
        myrec[nmy++] = (unsigned int)src | ((unsigned int)dst << 16);
    }

    for (int side = 0; side < 2; side++) {       // 0 = S (by src), 1 = D (by dst)
        for (int i = tid; i < NCB_MAX; i += 256) cnt[i] = 0;
        __syncthreads();
        int mybkt[CHUNK / 256];
        for (int k = 0; k < nmy; k++) {
            unsigned int r = myrec[k];
            int node = side ? (int)(r >> 16) : (int)(r & 0xFFFFu);
            mybkt[k] = node >> CSH;
            atomicAdd(&cnt[mybkt[k]], 1);
        }
        __syncthreads();
        if (tid == 0) {
            int s = 0;
            for (int i = 0; i < ncb; i++) { off[i] = s; s += cnt[i]; }
        }
        __syncthreads();
        for (int i = tid; i < NCB_MAX; i += 256) cur[i] = off[i];
        __syncthreads();
        for (int k = 0; k < nmy; k++) {
            int p = atomicAdd(&cur[mybkt[k]], 1);
            srt[p] = myrec[k];
        }
        __syncthreads();
        int* gcur = side ? gcurD : gcurS;
        for (int i = tid; i < ncb; i += 256) {
            int c = cnt[i];
            gpos[i] = c ? atomicAdd(&gcur[i], c) : 0;
        }
        __syncthreads();
        unsigned int* recX = side ? recD : recS;
        for (int i = tid; i < m; i += 256) {
            unsigned int r = srt[i];
            int node = side ? (int)(r >> 16) : (int)(r & 0xFFFFu);
            int cb = node >> CSH;
            recX[gpos[cb] + (i - off[cb])] = r;
        }
        __syncthreads();
    }
}

// block per (side, coarse bucket): build node-level CSR inside the bucket's
// private region. adjS stores dst (u16), adjD stores src (u16).
__global__ __launch_bounds__(256) void k_rebin(const unsigned int* __restrict__ recS,
                                               const unsigned int* __restrict__ recD,
                                               const int* __restrict__ baseS,
                                               const int* __restrict__ baseD,
                                               unsigned short* __restrict__ adjS,
                                               unsigned short* __restrict__ adjD,
                                               int* __restrict__ rowptrS,
                                               int* __restrict__ rowptrD,
                                               int ncb, int N) {
    __shared__ int cnt[1024];
    __shared__ int cur[1024];
    __shared__ int tsum[256];
    const int tid  = threadIdx.x;
    const int side = (blockIdx.x >= ncb) ? 1 : 0;      // 0 = S, 1 = D
    const int cb   = side ? blockIdx.x - ncb : blockIdx.x;
    const unsigned int* rec = side ? recD : recS;
    const int* base = side ? baseD : baseS;
    const int b0 = base[cb], b1 = base[cb + 1];
    const int tot_rec = b1 - b0;

    for (int i = tid; i < 1024; i += 256) cnt[i] = 0;
    __syncthreads();
    for (int i = tid; i < tot_rec; i += 256) {
        unsigned int r = rec[b0 + i];
        int node = side ? (int)(r >> 16) : (int)(r & 0xFFFFu);
        atomicAdd(&cnt[node & 1023], 1);
    }
    __syncthreads();
    // exclusive scan of cnt[1024] (4 per thread)
    int c0 = cnt[tid * 4], c1 = cnt[tid * 4 + 1], c2 = cnt[tid * 4 + 2], c3 = cnt[tid * 4 + 3];
    int e1 = c0, e2 = c0 + c1, e3 = c0 + c1 + c2;
    int tot = e3 + c3;
    tsum[tid] = tot;
    __syncthreads();
    for (int o = 1; o < 256; o <<= 1) {
        int v = (tid >= o) ? tsum[tid - o] : 0;
        __syncthreads();
        tsum[tid] += v;
        __syncthreads();
    }
    int ex = tsum[tid] - tot;
    cnt[tid * 4]     = ex;
    cnt[tid * 4 + 1] = ex + e1;
    cnt[tid * 4 + 2] = ex + e2;
    cnt[tid * 4 + 3] = ex + e3;
    __syncthreads();
    int* rowptr = side ? rowptrD : rowptrS;
    for (int k = tid; k < 1024; k += 256) {
        int node = (cb << CSH) + k;
        if (node < N) rowptr[node] = b0 + cnt[k];
        cur[k] = cnt[k];
    }
    __syncthreads();
    unsigned short* adj = side ? adjD : adjS;
    for (int i = tid; i < tot_rec; i += 256) {
        unsigned int r = rec[b0 + i];
        int node = side ? (int)(r >> 16) : (int)(r & 0xFFFFu);
        unsigned short other = side ? (unsigned short)(r & 0xFFFFu)
                                    : (unsigned short)(r >> 16);
        int p = atomicAdd(&cur[node & 1023], 1);
        adj[b0 + p] = other;
    }
}

// rdenom[n][h] = 1/(sum over out-edges exp(leaky(al[dst]+ar[n])) + 1e-16)
__global__ __launch_bounds__(256) void k_denom(const int* __restrict__ rowptrS,
                                               const unsigned short* __restrict__ adjS,
                                               const float* __restrict__ al,
                                               const float* __restrict__ ar,
                                               float* __restrict__ rdenom, int N) {
    int n = blockIdx.x * 256 + threadIdx.x;
    if (n >= N) return;
    int beg = rowptrS[n], end = rowptrS[n + 1];
    float4 arv = *(const float4*)(ar + n * NH);
    float s0 = 0.f, s1 = 0.f, s2 = 0.f, s3 = 0.f;
    for (int i = beg; i < end; i++) {
        int d = adjS[i];
        float4 av = *(const float4*)(al + d * NH);
        float a0 = av.x + arv.x, a1 = av.y + arv.y;
        float a2 = av.z + arv.z, a3 = av.w + arv.w;
        a0 = (a0 > 0.f) ? a0 : NEG_SLOPE * a0;
        a1 = (a1 > 0.f) ? a1 : NEG_SLOPE * a1;
        a2 = (a2 > 0.f) ? a2 : NEG_SLOPE * a2;
        a3 = (a3 > 0.f) ? a3 : NEG_SLOPE * a3;
        s0 += __expf(a0); s1 += __expf(a1);
        s2 += __expf(a2); s3 += __expf(a3);
    }
    float4 r;
    r.x = 1.0f / (s0 + 1e-16f);
    r.y = 1.0f / (s1 + 1e-16f);
    r.z = 1.0f / (s2 + 1e-16f);
    r.w = 1.0f / (s3 + 1e-16f);
    *(float4*)(rdenom + n * NH) = r;
}

// agg over dst-CSR: out[n][c] = bias[c] + sum_i bf2f(h_bf[s_i][c]) * w_i,
// w_i = exp(leaky(al[n][hh]+ar[s_i][hh])) * rdenom[s_i][hh] inline.
// 4 nodes/block, 64 threads/node, 2 channels/thread.
__global__ __launch_bounds__(256) void k_agg(const int* __restrict__ rowptrD,
                                             const unsigned short* __restrict__ adjD,
                                             const float* __restrict__ al,
                                             const float* __restrict__ ar,
                                             const float* __restrict__ rdenom,
                                             const unsigned short* __restrict__ h_bf,
                                             const float* __restrict__ bias,
                                             float* __restrict__ out, int N) {
    int n = blockIdx.x * 4 + (threadIdx.x >> 6);
    if (n >= N) return;
    int lane = threadIdx.x & 63;
    int c    = lane * 2;
    int hh   = lane >> 4;
    int beg = rowptrD[n], end = rowptrD[n + 1];
    float alv = al[n * NH + hh];
    float a0 = bias[c], a1 = bias[c + 1];
    float b0 = 0.f, b1 = 0.f;
    int i = beg;
    for (; i + 2 <= end; i += 2) {
        int s0 = adjD[i];
        int s1 = adjD[i + 1];
        float e0 = alv + ar[s0 * NH + hh];
        float e1 = alv + ar[s1 * NH + hh];
        e0 = (e0 > 0.f) ? e0 : NEG_SLOPE * e0;
        e1 = (e1 > 0.f) ? e1 : NEG_SLOPE * e1;
        float w0 = __expf(e0) * rdenom[s0 * NH + hh];
        float w1 = __expf(e1) * rdenom[s1 * NH + hh];
        ushort2 u0 = *(const ushort2*)(h_bf + (size_t)s0 * HC + c);
        ushort2 u1 = *(const ushort2*)(h_bf + (size_t)s1 * HC + c);
        a0 += bf2f(u0.x) * w0;
        a1 += bf2f(u0.y) * w0;
        b0 += bf2f(u1.x) * w1;
        b1 += bf2f(u1.y) * w1;
    }
    if (i < end) {
        int s0 = adjD[i];
        float e0 = alv + ar[s0 * NH + hh];
        e0 = (e0 > 0.f) ? e0 : NEG_SLOPE * e0;
        float w0 = __expf(e0) * rdenom[s0 * NH + hh];
        ushort2 u0 = *(const ushort2*)(h_bf + (size_t)s0 * HC + c);
        a0 += bf2f(u0.x) * w0;
        a1 += bf2f(u0.y) * w0;
    }
    *(float2*)(out + (size_t)n * HC + c) = make_float2(a0 + b0, a1 + b1);
}

extern "C" void kernel_launch(void* const* d_in, const int* in_sizes, int n_in,
                              void* d_out, int out_size, void* d_ws, size_t ws_size,
                              hipStream_t stream) {
    const float* x    = (const float*)d_in[0];
    const float* W    = (const float*)d_in[1];
    const float* att  = (const float*)d_in[2];
    const float* bias = (const float*)d_in[3];
    const int*   ei   = (const int*)d_in[4];

    const int N  = in_sizes[0] / IND;     // 50000
    const int E  = in_sizes[4] / 2;       // 800000
    const int NE = E + N;
    const int ncb = (N + (1 << CSH) - 1) >> CSH;   // 49
    float* out = (float*)d_out;
    const int nodeTot = N * NH;

    // ws layout (16B-aligned chunks where needed)
    unsigned short* h_bf = (unsigned short*)d_ws;              // N*128 u16 = 12.8MB
    float* al      = (float*)(h_bf + (size_t)N * HC);          // N*4 f32
    float* ar      = al + nodeTot;                             // N*4
    float* rdenom  = ar + nodeTot;                             // N*4
    unsigned int* recS = (unsigned int*)(rdenom + nodeTot);    // NE u32 = 3.4MB
    unsigned int* recD = recS + NE;                            // NE u32
    unsigned short* adjS = (unsigned short*)(recD + NE);       // NE u16 = 1.7MB
    unsigned short* adjD = adjS + NE;                          // NE u16
    int* rowptrS = (int*)(adjD + NE + (NE & 1));               // N+1
    int* rowptrD = rowptrS + (N + 2);                          // N+1
    int* histS   = rowptrD + (N + 2);                          // ncb
    int* histD   = histS + NCB_MAX;                            // ncb
    int* baseS   = histD + NCB_MAX;                            // ncb+1
    int* baseD   = baseS + (NCB_MAX + 1);                      // ncb+1
    int* curS    = baseD + (NCB_MAX + 1);                      // ncb
    int* curD    = curS + NCB_MAX;                             // ncb

    k_init0<<<1, 256, 0, stream>>>(histS, histD, ncb);
    k_gemm<<<(N + 63) / 64, 256, 0, stream>>>(x, W, h_bf, N);
    k_node_dots<<<(nodeTot + 255) / 256, 256, 0, stream>>>(h_bf, att, al, ar, N);
    k_hist<<<128, 256, 0, stream>>>(ei, histS, histD, E, NE, ncb);
    k_scanC<<<1, 64, 0, stream>>>(histS, histD, baseS, baseD, curS, curD,
                                  rowptrS, rowptrD, ncb, NE, N);
    k_scatterC<<<(NE + CHUNK - 1) / CHUNK, 256, 0, stream>>>(ei, curS, curD,
                                                             recS, recD, E, NE, ncb);
    k_rebin<<<2 * ncb, 256, 0, stream>>>(recS, recD, baseS, baseD, adjS, adjD,
                                         rowptrS, rowptrD, ncb, N);
    k_denom<<<(N + 255) / 256, 256, 0, stream>>>(rowptrS, adjS, al, ar, rdenom, N);
    k_agg<<<(N + 3) / 4, 256, 0, stream>>>(rowptrD, adjD, al, ar, rdenom, h_bf, bias, out, N);
}

// Round 7
// 274.847 us; speedup vs baseline: 1.6627x; 1.0864x over previous
//
#include <hip/hip_runtime.h>
#include <math.h>

// GAT layer: N=50000, E=800000, IN=256, H=4, C=32.
// R7: MFMA bf16 GEMM (mfma_f32_16x16x32_bf16) with fused node_dots epilogue.
// CSR build (R6 two-level bucketed, block-private writes) unchanged.
//   k_wprep    : W fp32 (k-major) -> WT_bf bf16 [c][k] (one-time, tiny)
//   k_gemm_mfma: h_bf = bf16(x @ W), 64-row tile, 4 waves x 8 col-tiles;
//                epilogue: C->LDS -> coalesced bf16 store + al/ar dots
//   k_hist/scanC/scatterC/rebin : bucketed CSR (src & dst)
//   k_denom    : gather over src-CSR -> rdenom
//   k_agg      : gather over dst-CSR, w recomputed inline, bias fused

#define NH 4
#define CH 32
#define HC 128
#define IND 256
#define NEG_SLOPE 0.2f
#define CSH 10          // coarse bucket = 1024 nodes
#define NCB_MAX 64
#define CHUNK 4096

typedef __attribute__((ext_vector_type(8))) short bf16x8;
typedef __attribute__((ext_vector_type(4))) float f32x4;

__device__ __forceinline__ unsigned short f2bf(float f) {
    unsigned int u = __float_as_uint(f);
    unsigned int r = (u + 0x7FFFu + ((u >> 16) & 1u)) >> 16;   // RNE
    return (unsigned short)r;
}
__device__ __forceinline__ float bf2f(unsigned short s) {
    return __uint_as_float(((unsigned int)s) << 16);
}

__global__ __launch_bounds__(256) void k_init0(int* __restrict__ histS,
                                               int* __restrict__ histD, int ncb) {
    int t = threadIdx.x;
    if (t < ncb) { histS[t] = 0; histD[t] = 0; }
}

// WT_bf[c][k] = bf16(W[k][c]) — one-time transpose+convert (32k elems).
__global__ __launch_bounds__(256) void k_wprep(const float* __restrict__ W,
                                               unsigned short* __restrict__ WT_bf) {
    int t = blockIdx.x * 256 + threadIdx.x;
    if (t >= IND * HC) return;
    int c = t >> 8;           // 0..127
    int k = t & 255;          // 0..255
    WT_bf[t] = f2bf(W[k * HC + c]);
}

// h_bf = bf16(x @ W) via MFMA. Block: 256 thr = 4 waves, 64 rows x 128 cols.
// K chunked by 64. LDS: xs[64][72] bf16 + wsT[128][72] bf16 (27.6KB), then
// reused as cs[64][129] f32 (33KB) for the epilogue.
// Fragment layouts (gfx950, measured m89/m120):
//   A: lane holds A[m=lane&15][k=quad*8+j], j=0..7
//   B: lane holds B[n=lane&15][k=quad*8+j]
//   C: lane holds C[row=quad*4+reg][col=lane&15]
__global__ __launch_bounds__(256) void k_gemm_mfma(const float* __restrict__ x,
                                                   const unsigned short* __restrict__ WT_bf,
                                                   const float* __restrict__ att,
                                                   unsigned short* __restrict__ h_bf,
                                                   float* __restrict__ al,
                                                   float* __restrict__ ar, int N) {
    __shared__ float cs[64 * 129];                     // 33 KB, aliased below
    unsigned short* xs  = (unsigned short*)cs;         // [64][72]
    unsigned short* wsT = xs + 64 * 72;                // [128][72]

    const int tid  = threadIdx.x;
    const int row0 = blockIdx.x * 64;
    const int wave = tid >> 6;
    const int lane = tid & 63;
    const int m16  = lane & 15;
    const int quad = lane >> 4;

    f32x4 acc[8];
#pragma unroll
    for (int t = 0; t < 8; t++) acc[t] = (f32x4){0.f, 0.f, 0.f, 0.f};

    for (int kc = 0; kc < 4; kc++) {
        // stage xs: 64 rows x 64 k (fp32 -> bf16), 4 float4 per thread
#pragma unroll
        for (int j = 0; j < 4; j++) {
            int lin = tid + j * 256;          // 0..1023 float4s
            int r   = lin >> 4;
            int k4  = (lin & 15) * 4;
            int row = row0 + r;
            float4 v = make_float4(0.f, 0.f, 0.f, 0.f);
            if (row < N) v = *(const float4*)(x + (size_t)row * IND + kc * 64 + k4);
            ushort4 o;
            o.x = f2bf(v.x); o.y = f2bf(v.y); o.z = f2bf(v.z); o.w = f2bf(v.w);
            *(ushort4*)(xs + r * 72 + k4) = o;
        }
        // stage wsT: 128 cols x 64 k from pre-transposed WT_bf (16B copies)
#pragma unroll
        for (int j = 0; j < 4; j++) {
            int lin = tid + j * 256;          // 0..1023 16B-chunks
            int c   = lin >> 3;
            int k8  = (lin & 7) * 8;
            *(int4*)(wsT + c * 72 + k8) =
                *(const int4*)(WT_bf + c * IND + kc * 64 + k8);
        }
        __syncthreads();
        const unsigned short* xrow = xs + (wave * 16 + m16) * 72;
#pragma unroll
        for (int k0 = 0; k0 < 64; k0 += 32) {
            bf16x8 a = *(const bf16x8*)(xrow + k0 + quad * 8);
#pragma unroll
            for (int t = 0; t < 8; t++) {
                bf16x8 b = *(const bf16x8*)(wsT + (t * 16 + m16) * 72 + k0 + quad * 8);
                acc[t] = __builtin_amdgcn_mfma_f32_16x16x32_bf16(a, b, acc[t], 0, 0, 0);
            }
        }
        __syncthreads();
    }

    // epilogue: C frags -> cs (fp32), then coalesced bf16 stores + node dots
#pragma unroll
    for (int t = 0; t < 8; t++)
#pragma unroll
        for (int r = 0; r < 4; r++)
            cs[(wave * 16 + quad * 4 + r) * 129 + t * 16 + m16] = acc[t][r];
    __syncthreads();

    int rloc = tid >> 2, head = tid & 3;
    int row  = row0 + rloc;
    if (row < N) {
        const float* cr = cs + rloc * 129 + head * CH;
#pragma unroll
        for (int c = 0; c < CH; c += 4) {
            ushort4 o;
            o.x = f2bf(cr[c]);     o.y = f2bf(cr[c + 1]);
            o.z = f2bf(cr[c + 2]); o.w = f2bf(cr[c + 3]);
            *(ushort4*)(h_bf + (size_t)row * HC + head * CH + c) = o;
        }
        const float* wl = att + head * (2 * CH);
        float sl = 0.f, sr = 0.f;
#pragma unroll
        for (int c = 0; c < CH; c++) {
            float hv = cr[c];
            sl += hv * wl[c];
            sr += hv * wl[CH + c];
        }
        al[row * NH + head] = sl;
        ar[row * NH + head] = sr;
    }
}

// coarse histograms, LDS-staged (few global atomics).
__global__ __launch_bounds__(256) void k_hist(const int* __restrict__ ei,
                                              int* __restrict__ histS,
                                              int* __restrict__ histD,
                                              int E, int NE, int ncb) {
    __shared__ int hs[NCB_MAX], hd[NCB_MAX];
    for (int i = threadIdx.x; i < NCB_MAX; i += 256) { hs[i] = 0; hd[i] = 0; }
    __syncthreads();
    for (int t = blockIdx.x * 256 + threadIdx.x; t < NE; t += gridDim.x * 256) {
        int src, dst;
        if (t < E) { src = ei[t]; dst = ei[E + t]; }
        else       { src = dst = t - E; }
        atomicAdd(&hs[src >> CSH], 1);
        atomicAdd(&hd[dst >> CSH], 1);
    }
    __syncthreads();
    for (int i = threadIdx.x; i < ncb; i += 256) {
        if (hs[i]) atomicAdd(&histS[i], hs[i]);
        if (hd[i]) atomicAdd(&histD[i], hd[i]);
    }
}

// serial exclusive scan over ncb coarse buckets, both sides; init cursors.
__global__ __launch_bounds__(64) void k_scanC(const int* __restrict__ histS,
                                              const int* __restrict__ histD,
                                              int* __restrict__ baseS,
                                              int* __restrict__ baseD,
                                              int* __restrict__ curS,
                                              int* __restrict__ curD,
                                              int* __restrict__ rowptrS,
                                              int* __restrict__ rowptrD,
                                              int ncb, int NE, int N) {
    if (threadIdx.x == 0) {
        int s = 0;
        for (int i = 0; i < ncb; i++) { baseS[i] = s; curS[i] = s; s += histS[i]; }
        baseS[ncb] = s;
        int d = 0;
        for (int i = 0; i < ncb; i++) { baseD[i] = d; curD[i] = d; d += histD[i]; }
        baseD[ncb] = d;
        rowptrS[N] = NE;
        rowptrD[N] = NE;
    }
}

// chunked scatter into coarse streams: LDS-binned, appended in long runs so
// every record line is written (almost always) by one block.
__global__ __launch_bounds__(256) void k_scatterC(const int* __restrict__ ei,
                                                  int* __restrict__ gcurS,
                                                  int* __restrict__ gcurD,
                                                  unsigned int* __restrict__ recS,
                                                  unsigned int* __restrict__ recD,
                                                  int E, int NE, int ncb) {
    __shared__ unsigned int srt[CHUNK];          // 16 KB
    __shared__ int cnt[NCB_MAX], off[NCB_MAX], cur[NCB_MAX], gpos[NCB_MAX];
    const int tid = threadIdx.x;
    const int t0  = blockIdx.x * CHUNK;
    const int m   = min(CHUNK, NE - t0);

    unsigned int myrec[CHUNK / 256];
    int nmy = 0;
    for (int i = tid; i < m; i += 256) {
        int t = t0 + i;
        int src, dst;
        if (t < E) { src = ei[t]; dst = ei[E + t]; }
        else       { src = dst = t - E; }
        myrec[nmy++] = (unsigned int)src | ((unsigned int)dst << 16);
    }

    for (int side = 0; side < 2; side++) {       // 0 = S (by src), 1 = D (by dst)
        for (int i = tid; i < NCB_MAX; i += 256) cnt[i] = 0;
        __syncthreads();
        int mybkt[CHUNK / 256];
        for (int k = 0; k < nmy; k++) {
            unsigned int r = myrec[k];
            int node = side ? (int)(r >> 16) : (int)(r & 0xFFFFu);
            mybkt[k] = node >> CSH;
            atomicAdd(&cnt[mybkt[k]], 1);
        }
        __syncthreads();
        if (tid == 0) {
            int s = 0;
            for (int i = 0; i < ncb; i++) { off[i] = s; s += cnt[i]; }
        }
        __syncthreads();
        for (int i = tid; i < NCB_MAX; i += 256) cur[i] = off[i];
        __syncthreads();
        for (int k = 0; k < nmy; k++) {
            int p = atomicAdd(&cur[mybkt[k]], 1);
            srt[p] = myrec[k];
        }
        __syncthreads();
        int* gcur = side ? gcurD : gcurS;
        for (int i = tid; i < ncb; i += 256) {
            int c = cnt[i];
            gpos[i] = c ? atomicAdd(&gcur[i], c) : 0;
        }
        __syncthreads();
        unsigned int* recX = side ? recD : recS;
        for (int i = tid; i < m; i += 256) {
            unsigned int r = srt[i];
            int node = side ? (int)(r >> 16) : (int)(r & 0xFFFFu);
            int cb = node >> CSH;
            recX[gpos[cb] + (i - off[cb])] = r;
        }
        __syncthreads();
    }
}

// block per (side, coarse bucket): build node-level CSR inside the bucket's
// private region. adjS stores dst (u16), adjD stores src (u16).
__global__ __launch_bounds__(256) void k_rebin(const unsigned int* __restrict__ recS,
                                               const unsigned int* __restrict__ recD,
                                               const int* __restrict__ baseS,
                                               const int* __restrict__ baseD,
                                               unsigned short* __restrict__ adjS,
                                               unsigned short* __restrict__ adjD,
                                               int* __restrict__ rowptrS,
                                               int* __restrict__ rowptrD,
                                               int ncb, int N) {
    __shared__ int cnt[1024];
    __shared__ int cur[1024];
    __shared__ int tsum[256];
    const int tid  = threadIdx.x;
    const int side = (blockIdx.x >= ncb) ? 1 : 0;
    const int cb   = side ? blockIdx.x - ncb : blockIdx.x;
    const unsigned int* rec = side ? recD : recS;
    const int* base = side ? baseD : baseS;
    const int b0 = base[cb], b1 = base[cb + 1];
    const int tot_rec = b1 - b0;

    for (int i = tid; i < 1024; i += 256) cnt[i] = 0;
    __syncthreads();
    for (int i = tid; i < tot_rec; i += 256) {
        unsigned int r = rec[b0 + i];
        int node = side ? (int)(r >> 16) : (int)(r & 0xFFFFu);
        atomicAdd(&cnt[node & 1023], 1);
    }
    __syncthreads();
    int c0 = cnt[tid * 4], c1 = cnt[tid * 4 + 1], c2 = cnt[tid * 4 + 2], c3 = cnt[tid * 4 + 3];
    int e1 = c0, e2 = c0 + c1, e3 = c0 + c1 + c2;
    int tot = e3 + c3;
    tsum[tid] = tot;
    __syncthreads();
    for (int o = 1; o < 256; o <<= 1) {
        int v = (tid >= o) ? tsum[tid - o] : 0;
        __syncthreads();
        tsum[tid] += v;
        __syncthreads();
    }
    int ex = tsum[tid] - tot;
    cnt[tid * 4]     = ex;
    cnt[tid * 4 + 1] = ex + e1;
    cnt[tid * 4 + 2] = ex + e2;
    cnt[tid * 4 + 3] = ex + e3;
    __syncthreads();
    int* rowptr = side ? rowptrD : rowptrS;
    for (int k = tid; k < 1024; k += 256) {
        int node = (cb << CSH) + k;
        if (node < N) rowptr[node] = b0 + cnt[k];
        cur[k] = cnt[k];
    }
    __syncthreads();
    unsigned short* adj = side ? adjD : adjS;
    for (int i = tid; i < tot_rec; i += 256) {
        unsigned int r = rec[b0 + i];
        int node = side ? (int)(r >> 16) : (int)(r & 0xFFFFu);
        unsigned short other = side ? (unsigned short)(r & 0xFFFFu)
                                    : (unsigned short)(r >> 16);
        int p = atomicAdd(&cur[node & 1023], 1);
        adj[b0 + p] = other;
    }
}

// rdenom[n][h] = 1/(sum over out-edges exp(leaky(al[dst]+ar[n])) + 1e-16)
__global__ __launch_bounds__(256) void k_denom(const int* __restrict__ rowptrS,
                                               const unsigned short* __restrict__ adjS,
                                               const float* __restrict__ al,
                                               const float* __restrict__ ar,
                                               float* __restrict__ rdenom, int N) {
    int n = blockIdx.x * 256 + threadIdx.x;
    if (n >= N) return;
    int beg = rowptrS[n], end = rowptrS[n + 1];
    float4 arv = *(const float4*)(ar + n * NH);
    float s0 = 0.f, s1 = 0.f, s2 = 0.f, s3 = 0.f;
    for (int i = beg; i < end; i++) {
        int d = adjS[i];
        float4 av = *(const float4*)(al + d * NH);
        float a0 = av.x + arv.x, a1 = av.y + arv.y;
        float a2 = av.z + arv.z, a3 = av.w + arv.w;
        a0 = (a0 > 0.f) ? a0 : NEG_SLOPE * a0;
        a1 = (a1 > 0.f) ? a1 : NEG_SLOPE * a1;
        a2 = (a2 > 0.f) ? a2 : NEG_SLOPE * a2;
        a3 = (a3 > 0.f) ? a3 : NEG_SLOPE * a3;
        s0 += __expf(a0); s1 += __expf(a1);
        s2 += __expf(a2); s3 += __expf(a3);
    }
    float4 r;
    r.x = 1.0f / (s0 + 1e-16f);
    r.y = 1.0f / (s1 + 1e-16f);
    r.z = 1.0f / (s2 + 1e-16f);
    r.w = 1.0f / (s3 + 1e-16f);
    *(float4*)(rdenom + n * NH) = r;
}

// agg over dst-CSR: out[n][c] = bias[c] + sum_i bf2f(h_bf[s_i][c]) * w_i,
// w_i = exp(leaky(al[n][hh]+ar[s_i][hh])) * rdenom[s_i][hh] inline.
__global__ __launch_bounds__(256) void k_agg(const int* __restrict__ rowptrD,
                                             const unsigned short* __restrict__ adjD,
                                             const float* __restrict__ al,
                                             const float* __restrict__ ar,
                                             const float* __restrict__ rdenom,
                                             const unsigned short* __restrict__ h_bf,
                                             const float* __restrict__ bias,
                                             float* __restrict__ out, int N) {
    int n = blockIdx.x * 4 + (threadIdx.x >> 6);
    if (n >= N) return;
    int lane = threadIdx.x & 63;
    int c    = lane * 2;
    int hh   = lane >> 4;
    int beg = rowptrD[n], end = rowptrD[n + 1];
    float alv = al[n * NH + hh];
    float a0 = bias[c], a1 = bias[c + 1];
    float b0 = 0.f, b1 = 0.f;
    int i = beg;
    for (; i + 2 <= end; i += 2) {
        int s0 = adjD[i];
        int s1 = adjD[i + 1];
        float e0 = alv + ar[s0 * NH + hh];
        float e1 = alv + ar[s1 * NH + hh];
        e0 = (e0 > 0.f) ? e0 : NEG_SLOPE * e0;
        e1 = (e1 > 0.f) ? e1 : NEG_SLOPE * e1;
        float w0 = __expf(e0) * rdenom[s0 * NH + hh];
        float w1 = __expf(e1) * rdenom[s1 * NH + hh];
        ushort2 u0 = *(const ushort2*)(h_bf + (size_t)s0 * HC + c);
        ushort2 u1 = *(const ushort2*)(h_bf + (size_t)s1 * HC + c);
        a0 += bf2f(u0.x) * w0;
        a1 += bf2f(u0.y) * w0;
        b0 += bf2f(u1.x) * w1;
        b1 += bf2f(u1.y) * w1;
    }
    if (i < end) {
        int s0 = adjD[i];
        float e0 = alv + ar[s0 * NH + hh];
        e0 = (e0 > 0.f) ? e0 : NEG_SLOPE * e0;
        float w0 = __expf(e0) * rdenom[s0 * NH + hh];
        ushort2 u0 = *(const ushort2*)(h_bf + (size_t)s0 * HC + c);
        a0 += bf2f(u0.x) * w0;
        a1 += bf2f(u0.y) * w0;
    }
    *(float2*)(out + (size_t)n * HC + c) = make_float2(a0 + b0, a1 + b1);
}

extern "C" void kernel_launch(void* const* d_in, const int* in_sizes, int n_in,
                              void* d_out, int out_size, void* d_ws, size_t ws_size,
                              hipStream_t stream) {
    const float* x    = (const float*)d_in[0];
    const float* W    = (const float*)d_in[1];
    const float* att  = (const float*)d_in[2];
    const float* bias = (const float*)d_in[3];
    const int*   ei   = (const int*)d_in[4];

    const int N  = in_sizes[0] / IND;     // 50000
    const int E  = in_sizes[4] / 2;       // 800000
    const int NE = E + N;
    const int ncb = (N + (1 << CSH) - 1) >> CSH;   // 49
    float* out = (float*)d_out;
    const int nodeTot = N * NH;

    // ws layout (16B-aligned chunks)
    unsigned short* h_bf  = (unsigned short*)d_ws;             // N*128 u16 = 12.8MB
    unsigned short* WT_bf = h_bf + (size_t)N * HC;             // 256*128 u16 = 64KB
    float* al      = (float*)(WT_bf + IND * HC);               // N*4 f32
    float* ar      = al + nodeTot;                             // N*4
    float* rdenom  = ar + nodeTot;                             // N*4
    unsigned int* recS = (unsigned int*)(rdenom + nodeTot);    // NE u32 = 3.4MB
    unsigned int* recD = recS + NE;                            // NE u32
    unsigned short* adjS = (unsigned short*)(recD + NE);       // NE u16 = 1.7MB
    unsigned short* adjD = adjS + NE;                          // NE u16
    int* rowptrS = (int*)(adjD + NE + (NE & 1));               // N+1
    int* rowptrD = rowptrS + (N + 2);                          // N+1
    int* histS   = rowptrD + (N + 2);                          // ncb
    int* histD   = histS + NCB_MAX;                            // ncb
    int* baseS   = histD + NCB_MAX;                            // ncb+1
    int* baseD   = baseS + (NCB_MAX + 1);                      // ncb+1
    int* curS    = baseD + (NCB_MAX + 1);                      // ncb
    int* curD    = curS + NCB_MAX;                             // ncb

    k_init0<<<1, 256, 0, stream>>>(histS, histD, ncb);
    k_wprep<<<(IND * HC + 255) / 256, 256, 0, stream>>>(W, WT_bf);
    k_gemm_mfma<<<(N + 63) / 64, 256, 0, stream>>>(x, WT_bf, att, h_bf, al, ar, N);
    k_hist<<<128, 256, 0, stream>>>(ei, histS, histD, E, NE, ncb);
    k_scanC<<<1, 64, 0, stream>>>(histS, histD, baseS, baseD, curS, curD,
                                  rowptrS, rowptrD, ncb, NE, N);
    k_scatterC<<<(NE + CHUNK - 1) / CHUNK, 256, 0, stream>>>(ei, curS, curD,
                                                             recS, recD, E, NE, ncb);
    k_rebin<<<2 * ncb, 256, 0, stream>>>(recS, recD, baseS, baseD, adjS, adjD,
                                         rowptrS, rowptrD, ncb, N);
    k_denom<<<(N + 255) / 256, 256, 0, stream>>>(rowptrS, adjS, al, ar, rdenom, N);
    k_agg<<<(N + 3) / 4, 256, 0, stream>>>(rowptrD, adjD, al, ar, rdenom, h_bf, bias, out, N);
}

// Round 8
// 249.559 us; speedup vs baseline: 1.8312x; 1.1013x over previous
//
#include <hip/hip_runtime.h>
#include <hip/hip_fp16.h>
#include <math.h>

// GAT layer: N=50000, E=800000, IN=256, H=4, C=32.
// R8: per-edge weights precomputed (k_wedge, half4/edge, dst-CSR order) so
//     k_agg is pure gather+FMA with 4-edge MLP; coarse buckets 1024->256
//     nodes (rebin 98->392 blocks); parallel scans replace serial ones.
// Pipeline: init0 -> wprep -> gemm_mfma(+node_dots fused) -> hist -> scanC
//        -> scatterC -> rebin -> denom -> wedge -> agg

#define NH 4
#define CH 32
#define HC 128
#define IND 256
#define NEG_SLOPE 0.2f
#define CSH 8           // coarse bucket = 256 nodes
#define NCB_MAX 256
#define CHUNK 4096

typedef __attribute__((ext_vector_type(8))) short bf16x8;
typedef __attribute__((ext_vector_type(4))) float f32x4;

__device__ __forceinline__ unsigned short f2bf(float f) {
    unsigned int u = __float_as_uint(f);
    unsigned int r = (u + 0x7FFFu + ((u >> 16) & 1u)) >> 16;   // RNE
    return (unsigned short)r;
}
__device__ __forceinline__ float bf2f(unsigned short s) {
    return __uint_as_float(((unsigned int)s) << 16);
}

__global__ __launch_bounds__(256) void k_init0(int* __restrict__ histS,
                                               int* __restrict__ histD, int ncb) {
    int t = threadIdx.x;
    if (t < ncb) { histS[t] = 0; histD[t] = 0; }
}

// WT_bf[c][k] = bf16(W[k][c]) — one-time transpose+convert.
__global__ __launch_bounds__(256) void k_wprep(const float* __restrict__ W,
                                               unsigned short* __restrict__ WT_bf) {
    int t = blockIdx.x * 256 + threadIdx.x;
    if (t >= IND * HC) return;
    int c = t >> 8;
    int k = t & 255;
    WT_bf[t] = f2bf(W[k * HC + c]);
}

// h_bf = bf16(x @ W) via MFMA; fused al/ar node-dot epilogue.
__global__ __launch_bounds__(256) void k_gemm_mfma(const float* __restrict__ x,
                                                   const unsigned short* __restrict__ WT_bf,
                                                   const float* __restrict__ att,
                                                   unsigned short* __restrict__ h_bf,
                                                   float* __restrict__ al,
                                                   float* __restrict__ ar, int N) {
    __shared__ float cs[64 * 129];                     // 33 KB, aliased below
    unsigned short* xs  = (unsigned short*)cs;         // [64][72]
    unsigned short* wsT = xs + 64 * 72;                // [128][72]

    const int tid  = threadIdx.x;
    const int row0 = blockIdx.x * 64;
    const int wave = tid >> 6;
    const int lane = tid & 63;
    const int m16  = lane & 15;
    const int quad = lane >> 4;

    f32x4 acc[8];
#pragma unroll
    for (int t = 0; t < 8; t++) acc[t] = (f32x4){0.f, 0.f, 0.f, 0.f};

    for (int kc = 0; kc < 4; kc++) {
#pragma unroll
        for (int j = 0; j < 4; j++) {
            int lin = tid + j * 256;
            int r   = lin >> 4;
            int k4  = (lin & 15) * 4;
            int row = row0 + r;
            float4 v = make_float4(0.f, 0.f, 0.f, 0.f);
            if (row < N) v = *(const float4*)(x + (size_t)row * IND + kc * 64 + k4);
            ushort4 o;
            o.x = f2bf(v.x); o.y = f2bf(v.y); o.z = f2bf(v.z); o.w = f2bf(v.w);
            *(ushort4*)(xs + r * 72 + k4) = o;
        }
#pragma unroll
        for (int j = 0; j < 4; j++) {
            int lin = tid + j * 256;
            int c   = lin >> 3;
            int k8  = (lin & 7) * 8;
            *(int4*)(wsT + c * 72 + k8) =
                *(const int4*)(WT_bf + c * IND + kc * 64 + k8);
        }
        __syncthreads();
        const unsigned short* xrow = xs + (wave * 16 + m16) * 72;
#pragma unroll
        for (int k0 = 0; k0 < 64; k0 += 32) {
            bf16x8 a = *(const bf16x8*)(xrow + k0 + quad * 8);
#pragma unroll
            for (int t = 0; t < 8; t++) {
                bf16x8 b = *(const bf16x8*)(wsT + (t * 16 + m16) * 72 + k0 + quad * 8);
                acc[t] = __builtin_amdgcn_mfma_f32_16x16x32_bf16(a, b, acc[t], 0, 0, 0);
            }
        }
        __syncthreads();
    }

#pragma unroll
    for (int t = 0; t < 8; t++)
#pragma unroll
        for (int r = 0; r < 4; r++)
            cs[(wave * 16 + quad * 4 + r) * 129 + t * 16 + m16] = acc[t][r];
    __syncthreads();

    int rloc = tid >> 2, head = tid & 3;
    int row  = row0 + rloc;
    if (row < N) {
        const float* cr = cs + rloc * 129 + head * CH;
#pragma unroll
        for (int c = 0; c < CH; c += 4) {
            ushort4 o;
            o.x = f2bf(cr[c]);     o.y = f2bf(cr[c + 1]);
            o.z = f2bf(cr[c + 2]); o.w = f2bf(cr[c + 3]);
            *(ushort4*)(h_bf + (size_t)row * HC + head * CH + c) = o;
        }
        const float* wl = att + head * (2 * CH);
        float sl = 0.f, sr = 0.f;
#pragma unroll
        for (int c = 0; c < CH; c++) {
            float hv = cr[c];
            sl += hv * wl[c];
            sr += hv * wl[CH + c];
        }
        al[row * NH + head] = sl;
        ar[row * NH + head] = sr;
    }
}

// coarse histograms, LDS-staged.
__global__ __launch_bounds__(256) void k_hist(const int* __restrict__ ei,
                                              int* __restrict__ histS,
                                              int* __restrict__ histD,
                                              int E, int NE, int ncb) {
    __shared__ int hs[NCB_MAX], hd[NCB_MAX];
    hs[threadIdx.x] = 0; hd[threadIdx.x] = 0;
    __syncthreads();
    for (int t = blockIdx.x * 256 + threadIdx.x; t < NE; t += gridDim.x * 256) {
        int src, dst;
        if (t < E) { src = ei[t]; dst = ei[E + t]; }
        else       { src = dst = t - E; }
        atomicAdd(&hs[src >> CSH], 1);
        atomicAdd(&hd[dst >> CSH], 1);
    }
    __syncthreads();
    int i = threadIdx.x;
    if (i < ncb) {
        if (hs[i]) atomicAdd(&histS[i], hs[i]);
        if (hd[i]) atomicAdd(&histD[i], hd[i]);
    }
}

// one block: parallel exclusive scan over ncb buckets, both sides.
__global__ __launch_bounds__(256) void k_scanC(const int* __restrict__ histS,
                                               const int* __restrict__ histD,
                                               int* __restrict__ baseS,
                                               int* __restrict__ baseD,
                                               int* __restrict__ curS,
                                               int* __restrict__ curD,
                                               int* __restrict__ rowptrS,
                                               int* __restrict__ rowptrD,
                                               int ncb, int NE, int N) {
    __shared__ int sc[256];
    int tid = threadIdx.x;
    // side S
    int v = (tid < ncb) ? histS[tid] : 0;
    sc[tid] = v;
    __syncthreads();
    for (int o = 1; o < 256; o <<= 1) {
        int t = (tid >= o) ? sc[tid - o] : 0;
        __syncthreads();
        sc[tid] += t;
        __syncthreads();
    }
    if (tid < ncb) { baseS[tid] = sc[tid] - v; curS[tid] = sc[tid] - v; }
    if (tid == 0) { baseS[ncb] = sc[255]; rowptrS[N] = NE; }
    __syncthreads();
    // side D
    v = (tid < ncb) ? histD[tid] : 0;
    sc[tid] = v;
    __syncthreads();
    for (int o = 1; o < 256; o <<= 1) {
        int t = (tid >= o) ? sc[tid - o] : 0;
        __syncthreads();
        sc[tid] += t;
        __syncthreads();
    }
    if (tid < ncb) { baseD[tid] = sc[tid] - v; curD[tid] = sc[tid] - v; }
    if (tid == 0) { baseD[ncb] = sc[255]; rowptrD[N] = NE; }
}

// chunked scatter into coarse streams, LDS-binned (full-line appends).
__global__ __launch_bounds__(256) void k_scatterC(const int* __restrict__ ei,
                                                  int* __restrict__ gcurS,
                                                  int* __restrict__ gcurD,
                                                  unsigned int* __restrict__ recS,
                                                  unsigned int* __restrict__ recD,
                                                  int E, int NE, int ncb) {
    __shared__ unsigned int srt[CHUNK];          // 16 KB
    __shared__ int cnt[NCB_MAX], off[NCB_MAX], cur[NCB_MAX], gpos[NCB_MAX], sc[256];
    const int tid = threadIdx.x;
    const int t0  = blockIdx.x * CHUNK;
    const int m   = min(CHUNK, NE - t0);

    unsigned int myrec[CHUNK / 256];
    int nmy = 0;
    for (int i = tid; i < m; i += 256) {
        int t = t0 + i;
        int src, dst;
        if (t < E) { src = ei[t]; dst = ei[E + t]; }
        else       { src = dst = t - E; }
        myrec[nmy++] = (unsigned int)src | ((unsigned int)dst << 16);
    }

    for (int side = 0; side < 2; side++) {       // 0 = S (by src), 1 = D (by dst)
        cnt[tid] = 0;
        __syncthreads();
        int mybkt[CHUNK / 256];
        for (int k = 0; k < nmy; k++) {
            unsigned int r = myrec[k];
            int node = side ? (int)(r >> 16) : (int)(r & 0xFFFFu);
            mybkt[k] = node >> CSH;
            atomicAdd(&cnt[mybkt[k]], 1);
        }
        __syncthreads();
        int v = cnt[tid];
        sc[tid] = v;
        __syncthreads();
        for (int o = 1; o < 256; o <<= 1) {
            int t = (tid >= o) ? sc[tid - o] : 0;
            __syncthreads();
            sc[tid] += t;
            __syncthreads();
        }
        off[tid] = sc[tid] - v;
        cur[tid] = sc[tid] - v;
        __syncthreads();
        for (int k = 0; k < nmy; k++) {
            int p = atomicAdd(&cur[mybkt[k]], 1);
            srt[p] = myrec[k];
        }
        __syncthreads();
        int* gcur = side ? gcurD : gcurS;
        if (tid < ncb) {
            int c = cnt[tid];
            gpos[tid] = c ? atomicAdd(&gcur[tid], c) : 0;
        }
        __syncthreads();
        unsigned int* recX = side ? recD : recS;
        for (int i = tid; i < m; i += 256) {
            unsigned int r = srt[i];
            int node = side ? (int)(r >> 16) : (int)(r & 0xFFFFu);
            int cb = node >> CSH;
            recX[gpos[cb] + (i - off[cb])] = r;
        }
        __syncthreads();
    }
}

// block per (side, coarse bucket): node-level CSR inside private region.
__global__ __launch_bounds__(256) void k_rebin(const unsigned int* __restrict__ recS,
                                               const unsigned int* __restrict__ recD,
                                               const int* __restrict__ baseS,
                                               const int* __restrict__ baseD,
                                               unsigned short* __restrict__ adjS,
                                               unsigned short* __restrict__ adjD,
                                               int* __restrict__ rowptrS,
                                               int* __restrict__ rowptrD,
                                               int ncb, int N) {
    __shared__ int cnt[256], cur[256], sc[256];
    const int tid  = threadIdx.x;
    const int side = (blockIdx.x >= ncb) ? 1 : 0;
    const int cb   = side ? blockIdx.x - ncb : blockIdx.x;
    const unsigned int* rec = side ? recD : recS;
    const int* base = side ? baseD : baseS;
    const int b0 = base[cb], b1 = base[cb + 1];
    const int tot_rec = b1 - b0;

    cnt[tid] = 0;
    __syncthreads();
    for (int i = tid; i < tot_rec; i += 256) {
        unsigned int r = rec[b0 + i];
        int node = side ? (int)(r >> 16) : (int)(r & 0xFFFFu);
        atomicAdd(&cnt[node & 255], 1);
    }
    __syncthreads();
    int v = cnt[tid];
    sc[tid] = v;
    __syncthreads();
    for (int o = 1; o < 256; o <<= 1) {
        int t = (tid >= o) ? sc[tid - o] : 0;
        __syncthreads();
        sc[tid] += t;
        __syncthreads();
    }
    int ex = sc[tid] - v;
    int node_g = (cb << CSH) + tid;
    int* rowptr = side ? rowptrD : rowptrS;
    if (node_g < N) rowptr[node_g] = b0 + ex;
    cur[tid] = ex;
    __syncthreads();
    unsigned short* adj = side ? adjD : adjS;
    for (int i = tid; i < tot_rec; i += 256) {
        unsigned int r = rec[b0 + i];
        int node = side ? (int)(r >> 16) : (int)(r & 0xFFFFu);
        unsigned short other = side ? (unsigned short)(r & 0xFFFFu)
                                    : (unsigned short)(r >> 16);
        int p = atomicAdd(&cur[node & 255], 1);
        adj[b0 + p] = other;
    }
}

// rdenom[n][h] = 1/(sum over out-edges exp(leaky(al[dst]+ar[n])) + 1e-16)
__global__ __launch_bounds__(256) void k_denom(const int* __restrict__ rowptrS,
                                               const unsigned short* __restrict__ adjS,
                                               const float* __restrict__ al,
                                               const float* __restrict__ ar,
                                               float* __restrict__ rdenom, int N) {
    int n = blockIdx.x * 256 + threadIdx.x;
    if (n >= N) return;
    int beg = rowptrS[n], end = rowptrS[n + 1];
    float4 arv = *(const float4*)(ar + n * NH);
    float s0 = 0.f, s1 = 0.f, s2 = 0.f, s3 = 0.f;
    int i = beg;
    for (; i + 2 <= end; i += 2) {
        int d0 = adjS[i], d1 = adjS[i + 1];
        float4 av0 = *(const float4*)(al + d0 * NH);
        float4 av1 = *(const float4*)(al + d1 * NH);
        float a0 = av0.x + arv.x, a1 = av0.y + arv.y;
        float a2 = av0.z + arv.z, a3 = av0.w + arv.w;
        float c0 = av1.x + arv.x, c1 = av1.y + arv.y;
        float c2 = av1.z + arv.z, c3 = av1.w + arv.w;
        a0 = (a0 > 0.f) ? a0 : NEG_SLOPE * a0;
        a1 = (a1 > 0.f) ? a1 : NEG_SLOPE * a1;
        a2 = (a2 > 0.f) ? a2 : NEG_SLOPE * a2;
        a3 = (a3 > 0.f) ? a3 : NEG_SLOPE * a3;
        c0 = (c0 > 0.f) ? c0 : NEG_SLOPE * c0;
        c1 = (c1 > 0.f) ? c1 : NEG_SLOPE * c1;
        c2 = (c2 > 0.f) ? c2 : NEG_SLOPE * c2;
        c3 = (c3 > 0.f) ? c3 : NEG_SLOPE * c3;
        s0 += __expf(a0) + __expf(c0);
        s1 += __expf(a1) + __expf(c1);
        s2 += __expf(a2) + __expf(c2);
        s3 += __expf(a3) + __expf(c3);
    }
    if (i < end) {
        int d0 = adjS[i];
        float4 av = *(const float4*)(al + d0 * NH);
        float a0 = av.x + arv.x, a1 = av.y + arv.y;
        float a2 = av.z + arv.z, a3 = av.w + arv.w;
        a0 = (a0 > 0.f) ? a0 : NEG_SLOPE * a0;
        a1 = (a1 > 0.f) ? a1 : NEG_SLOPE * a1;
        a2 = (a2 > 0.f) ? a2 : NEG_SLOPE * a2;
        a3 = (a3 > 0.f) ? a3 : NEG_SLOPE * a3;
        s0 += __expf(a0); s1 += __expf(a1);
        s2 += __expf(a2); s3 += __expf(a3);
    }
    float4 r;
    r.x = 1.0f / (s0 + 1e-16f);
    r.y = 1.0f / (s1 + 1e-16f);
    r.z = 1.0f / (s2 + 1e-16f);
    r.w = 1.0f / (s3 + 1e-16f);
    *(float4*)(rdenom + n * NH) = r;
}

// wD[i][hh] = half( exp(leaky(al[n][hh]+ar[s][hh])) * rdenom[s][hh] ),
// dst-CSR order. One thread per dst node.
__global__ __launch_bounds__(256) void k_wedge(const int* __restrict__ rowptrD,
                                               const unsigned short* __restrict__ adjD,
                                               const float* __restrict__ al,
                                               const float* __restrict__ ar,
                                               const float* __restrict__ rdenom,
                                               unsigned short* __restrict__ wD, int N) {
    int n = blockIdx.x * 256 + threadIdx.x;
    if (n >= N) return;
    int beg = rowptrD[n], end = rowptrD[n + 1];
    float4 alv = *(const float4*)(al + n * NH);
    for (int i = beg; i < end; i++) {
        int s = adjD[i];
        float4 rv = *(const float4*)(ar + s * NH);
        float4 dv = *(const float4*)(rdenom + s * NH);
        float a0 = alv.x + rv.x, a1 = alv.y + rv.y;
        float a2 = alv.z + rv.z, a3 = alv.w + rv.w;
        a0 = (a0 > 0.f) ? a0 : NEG_SLOPE * a0;
        a1 = (a1 > 0.f) ? a1 : NEG_SLOPE * a1;
        a2 = (a2 > 0.f) ? a2 : NEG_SLOPE * a2;
        a3 = (a3 > 0.f) ? a3 : NEG_SLOPE * a3;
        ushort4 w;
        w.x = __half_as_ushort(__float2half(__expf(a0) * dv.x));
        w.y = __half_as_ushort(__float2half(__expf(a1) * dv.y));
        w.z = __half_as_ushort(__float2half(__expf(a2) * dv.z));
        w.w = __half_as_ushort(__float2half(__expf(a3) * dv.w));
        *(ushort4*)(wD + (size_t)i * NH) = w;
    }
}

// agg: pure gather+FMA. 4 nodes/block, 64 threads/node, 2 ch/thread,
// 4-edge unroll for MLP.
__global__ __launch_bounds__(256) void k_agg(const int* __restrict__ rowptrD,
                                             const unsigned short* __restrict__ adjD,
                                             const unsigned short* __restrict__ wD,
                                             const unsigned short* __restrict__ h_bf,
                                             const float* __restrict__ bias,
                                             float* __restrict__ out, int N) {
    int n = blockIdx.x * 4 + (threadIdx.x >> 6);
    if (n >= N) return;
    int lane = threadIdx.x & 63;
    int c    = lane * 2;
    int hh   = lane >> 4;
    int beg = rowptrD[n], end = rowptrD[n + 1];
    float a0 = bias[c], a1 = bias[c + 1];
    float b0 = 0.f, b1 = 0.f;
    int i = beg;
    for (; i + 4 <= end; i += 4) {
        int s0 = adjD[i],     s1 = adjD[i + 1];
        int s2 = adjD[i + 2], s3 = adjD[i + 3];
        float w0 = __half2float(__ushort_as_half(wD[(size_t)i * NH + hh]));
        float w1 = __half2float(__ushort_as_half(wD[(size_t)(i + 1) * NH + hh]));
        float w2 = __half2float(__ushort_as_half(wD[(size_t)(i + 2) * NH + hh]));
        float w3 = __half2float(__ushort_as_half(wD[(size_t)(i + 3) * NH + hh]));
        ushort2 u0 = *(const ushort2*)(h_bf + (size_t)s0 * HC + c);
        ushort2 u1 = *(const ushort2*)(h_bf + (size_t)s1 * HC + c);
        ushort2 u2 = *(const ushort2*)(h_bf + (size_t)s2 * HC + c);
        ushort2 u3 = *(const ushort2*)(h_bf + (size_t)s3 * HC + c);
        a0 += bf2f(u0.x) * w0;  a1 += bf2f(u0.y) * w0;
        b0 += bf2f(u1.x) * w1;  b1 += bf2f(u1.y) * w1;
        a0 += bf2f(u2.x) * w2;  a1 += bf2f(u2.y) * w2;
        b0 += bf2f(u3.x) * w3;  b1 += bf2f(u3.y) * w3;
    }
    for (; i < end; i++) {
        int s0 = adjD[i];
        float w0 = __half2float(__ushort_as_half(wD[(size_t)i * NH + hh]));
        ushort2 u0 = *(const ushort2*)(h_bf + (size_t)s0 * HC + c);
        a0 += bf2f(u0.x) * w0;
        a1 += bf2f(u0.y) * w0;
    }
    *(float2*)(out + (size_t)n * HC + c) = make_float2(a0 + b0, a1 + b1);
}

extern "C" void kernel_launch(void* const* d_in, const int* in_sizes, int n_in,
                              void* d_out, int out_size, void* d_ws, size_t ws_size,
                              hipStream_t stream) {
    const float* x    = (const float*)d_in[0];
    const float* W    = (const float*)d_in[1];
    const float* att  = (const float*)d_in[2];
    const float* bias = (const float*)d_in[3];
    const int*   ei   = (const int*)d_in[4];

    const int N  = in_sizes[0] / IND;     // 50000
    const int E  = in_sizes[4] / 2;       // 800000
    const int NE = E + N;
    const int ncb = (N + (1 << CSH) - 1) >> CSH;   // 196
    float* out = (float*)d_out;
    const int nodeTot = N * NH;

    // ws layout
    unsigned short* h_bf  = (unsigned short*)d_ws;             // N*128 u16 = 12.8MB
    unsigned short* WT_bf = h_bf + (size_t)N * HC;             // 32K u16
    float* al      = (float*)(WT_bf + IND * HC);               // N*4 f32
    float* ar      = al + nodeTot;                             // N*4
    float* rdenom  = ar + nodeTot;                             // N*4
    unsigned int* recS = (unsigned int*)(rdenom + nodeTot);    // NE u32
    unsigned int* recD = recS + NE;                            // NE u32
    unsigned short* adjS = (unsigned short*)(recD + NE);       // NE u16
    unsigned short* adjD = adjS + NE;                          // NE u16
    unsigned short* wD   = adjD + NE + (NE & 1);               // NE*4 u16 = 6.8MB
    int* rowptrS = (int*)(wD + (size_t)NE * NH);               // N+1
    int* rowptrD = rowptrS + (N + 2);                          // N+1
    int* histS   = rowptrD + (N + 2);                          // ncb
    int* histD   = histS + NCB_MAX;                            // ncb
    int* baseS   = histD + NCB_MAX;                            // ncb+1
    int* baseD   = baseS + (NCB_MAX + 1);                      // ncb+1
    int* curS    = baseD + (NCB_MAX + 1);                      // ncb
    int* curD    = curS + NCB_MAX;                             // ncb

    k_init0<<<1, 256, 0, stream>>>(histS, histD, ncb);
    k_wprep<<<(IND * HC + 255) / 256, 256, 0, stream>>>(W, WT_bf);
    k_gemm_mfma<<<(N + 63) / 64, 256, 0, stream>>>(x, WT_bf, att, h_bf, al, ar, N);
    k_hist<<<256, 256, 0, stream>>>(ei, histS, histD, E, NE, ncb);
    k_scanC<<<1, 256, 0, stream>>>(histS, histD, baseS, baseD, curS, curD,
                                   rowptrS, rowptrD, ncb, NE, N);
    k_scatterC<<<(NE + CHUNK - 1) / CHUNK, 256, 0, stream>>>(ei, curS, curD,
                                                             recS, recD, E, NE, ncb);
    k_rebin<<<2 * ncb, 256, 0, stream>>>(recS, recD, baseS, baseD, adjS, adjD,
                                         rowptrS, rowptrD, ncb, N);
    k_denom<<<(N + 255) / 256, 256, 0, stream>>>(rowptrS, adjS, al, ar, rdenom, N);
    k_wedge<<<(N + 255) / 256, 256, 0, stream>>>(rowptrD, adjD, al, ar, rdenom, wD, N);
    k_agg<<<(N + 3) / 4, 256, 0, stream>>>(rowptrD, adjD, wD, h_bf, bias, out, N);
}

// Round 9
// 243.120 us; speedup vs baseline: 1.8797x; 1.0265x over previous
//
#include <hip/hip_runtime.h>
#include <hip/hip_fp16.h>
#include <math.h>

// GAT layer: N=50000, E=800000, IN=256, H=4, C=32.
// R9: barrier-free-K GEMM. W staged to LDS ONCE (64.5KB), then a 16-step
// K-loop with no __syncthreads: A-frags loaded global->reg per lane,
// 32x32x16 MFMA (wave = 32 rows x 128 cols -> half the LDS b-traffic/FLOP
// of 16x16x32). Epilogue via cs aliased over wsT (129-f32 stride, 2-way
// max banks); h_bf store + al/ar head-dots fully thread-local.
// Rest of pipeline (R8 bucketed CSR, denom, wedge, agg) unchanged.

#define NH 4
#define CH 32
#define HC 128
#define IND 256
#define NEG_SLOPE 0.2f
#define CSH 8           // coarse bucket = 256 nodes
#define NCB_MAX 256
#define CHUNK 4096

typedef __attribute__((ext_vector_type(8))) short bf16x8;
typedef __attribute__((ext_vector_type(16))) float f32x16;

__device__ __forceinline__ unsigned short f2bf(float f) {
    unsigned int u = __float_as_uint(f);
    unsigned int r = (u + 0x7FFFu + ((u >> 16) & 1u)) >> 16;   // RNE
    return (unsigned short)r;
}
__device__ __forceinline__ float bf2f(unsigned short s) {
    return __uint_as_float(((unsigned int)s) << 16);
}

__global__ __launch_bounds__(256) void k_init0(int* __restrict__ histS,
                                               int* __restrict__ histD, int ncb) {
    int t = threadIdx.x;
    if (t < ncb) { histS[t] = 0; histD[t] = 0; }
}

// WT_bf[c][k] = bf16(W[k][c]) — one-time transpose+convert.
__global__ __launch_bounds__(256) void k_wprep(const float* __restrict__ W,
                                               unsigned short* __restrict__ WT_bf) {
    int t = blockIdx.x * 256 + threadIdx.x;
    if (t >= IND * HC) return;
    int c = t >> 8;
    int k = t & 255;
    WT_bf[t] = f2bf(W[k * HC + c]);
}

// h_bf = bf16(x @ W) via 32x32x16 MFMA, barrier-free K-loop.
// Block: 256 thr = 4 waves x 32 rows = 128 rows; 4 col-tiles of 32.
// A-layout: lane holds A[m=lane&31][k=(lane>>5)*8+j]; B analogous;
// C/D: col=lane&31, row=(reg&3)+8*(reg>>2)+4*(lane>>5)  [m74/m101].
__global__ __launch_bounds__(256) void k_gemm_mfma(const float* __restrict__ x,
                                                   const unsigned short* __restrict__ WT_bf,
                                                   const float* __restrict__ att,
                                                   unsigned short* __restrict__ h_bf,
                                                   float* __restrict__ al,
                                                   float* __restrict__ ar, int N) {
    __shared__ float cs[128 * 129];                    // 66048 B
    unsigned short* wsT = (unsigned short*)cs;         // [128][258] = 66048 B

    const int tid  = threadIdx.x;
    const int row0 = blockIdx.x * 128;
    const int wave = tid >> 6;
    const int lane = tid & 63;
    const int n32  = lane & 31;
    const int half = lane >> 5;

    // stage full W once: thread copies half a column (128 shorts, int4 x16)
    {
        int c  = tid >> 1;
        int kh = (tid & 1) * 128;
        const unsigned short* src = WT_bf + c * IND + kh;
        unsigned short* dst = wsT + c * 258 + kh;
#pragma unroll
        for (int j = 0; j < 128; j += 8)
            *(int4*)(dst + j) = *(const int4*)(src + j);
    }
    __syncthreads();

    const int row   = row0 + wave * 32 + n32;
    const bool valid = row < N;
    const float* xrow = x + (size_t)row * IND + half * 8;

    f32x16 acc[4];
#pragma unroll
    for (int t = 0; t < 4; t++)
#pragma unroll
        for (int r = 0; r < 16; r++) acc[t][r] = 0.0f;

    // 16 K-steps of 16; NO barriers inside.
#pragma unroll 4
    for (int s = 0; s < 16; s++) {
        float4 v0 = make_float4(0.f, 0.f, 0.f, 0.f);
        float4 v1 = v0;
        if (valid) {
            v0 = *(const float4*)(xrow + s * 16);
            v1 = *(const float4*)(xrow + s * 16 + 4);
        }
        bf16x8 a;
        a[0] = (short)f2bf(v0.x); a[1] = (short)f2bf(v0.y);
        a[2] = (short)f2bf(v0.z); a[3] = (short)f2bf(v0.w);
        a[4] = (short)f2bf(v1.x); a[5] = (short)f2bf(v1.y);
        a[6] = (short)f2bf(v1.z); a[7] = (short)f2bf(v1.w);
#pragma unroll
        for (int t = 0; t < 4; t++) {
            bf16x8 b = *(const bf16x8*)(wsT + (t * 32 + n32) * 258 + s * 16 + half * 8);
            acc[t] = __builtin_amdgcn_mfma_f32_32x32x16_bf16(a, b, acc[t], 0, 0, 0);
        }
    }
    __syncthreads();   // wsT dead; cs aliases it

    // C frags -> cs (129-f32 stride: banks = rl + col, 2-way max = free)
#pragma unroll
    for (int t = 0; t < 4; t++)
#pragma unroll
        for (int r = 0; r < 16; r++) {
            int rl = wave * 32 + (r & 3) + 8 * (r >> 2) + 4 * half;
            cs[rl * 129 + t * 32 + n32] = acc[t][r];
        }
    __syncthreads();

    // epilogue: thread -> (row_local = tid>>1, col-half = tid&1 -> heads 2h,2h+1)
    const int rl   = tid >> 1;
    const int chf  = tid & 1;
    const int orow = row0 + rl;
    if (orow < N) {
        const float* cr = cs + rl * 129 + chf * 64;
        unsigned short* hp = h_bf + (size_t)orow * HC + chf * 64;
#pragma unroll
        for (int c = 0; c < 64; c += 8) {
            ushort4 o0, o1;
            o0.x = f2bf(cr[c]);     o0.y = f2bf(cr[c + 1]);
            o0.z = f2bf(cr[c + 2]); o0.w = f2bf(cr[c + 3]);
            o1.x = f2bf(cr[c + 4]); o1.y = f2bf(cr[c + 5]);
            o1.z = f2bf(cr[c + 6]); o1.w = f2bf(cr[c + 7]);
            *(ushort4*)(hp + c) = o0;
            *(ushort4*)(hp + c + 4) = o1;
        }
        const int h0 = 2 * chf, h1 = 2 * chf + 1;
        const float* w0 = att + h0 * (2 * CH);
        const float* w1 = att + h1 * (2 * CH);
        float sl0 = 0.f, sr0 = 0.f, sl1 = 0.f, sr1 = 0.f;
#pragma unroll
        for (int c = 0; c < CH; c++) {
            float v0 = cr[c];
            float v1 = cr[CH + c];
            sl0 += v0 * w0[c];  sr0 += v0 * w0[CH + c];
            sl1 += v1 * w1[c];  sr1 += v1 * w1[CH + c];
        }
        al[orow * NH + h0] = sl0;  al[orow * NH + h1] = sl1;
        ar[orow * NH + h0] = sr0;  ar[orow * NH + h1] = sr1;
    }
}

// coarse histograms, LDS-staged.
__global__ __launch_bounds__(256) void k_hist(const int* __restrict__ ei,
                                              int* __restrict__ histS,
                                              int* __restrict__ histD,
                                              int E, int NE, int ncb) {
    __shared__ int hs[NCB_MAX], hd[NCB_MAX];
    hs[threadIdx.x] = 0; hd[threadIdx.x] = 0;
    __syncthreads();
    for (int t = blockIdx.x * 256 + threadIdx.x; t < NE; t += gridDim.x * 256) {
        int src, dst;
        if (t < E) { src = ei[t]; dst = ei[E + t]; }
        else       { src = dst = t - E; }
        atomicAdd(&hs[src >> CSH], 1);
        atomicAdd(&hd[dst >> CSH], 1);
    }
    __syncthreads();
    int i = threadIdx.x;
    if (i < ncb) {
        if (hs[i]) atomicAdd(&histS[i], hs[i]);
        if (hd[i]) atomicAdd(&histD[i], hd[i]);
    }
}

// one block: parallel exclusive scan over ncb buckets, both sides.
__global__ __launch_bounds__(256) void k_scanC(const int* __restrict__ histS,
                                               const int* __restrict__ histD,
                                               int* __restrict__ baseS,
                                               int* __restrict__ baseD,
                                               int* __restrict__ curS,
                                               int* __restrict__ curD,
                                               int* __restrict__ rowptrS,
                                               int* __restrict__ rowptrD,
                                               int ncb, int NE, int N) {
    __shared__ int sc[256];
    int tid = threadIdx.x;
    int v = (tid < ncb) ? histS[tid] : 0;
    sc[tid] = v;
    __syncthreads();
    for (int o = 1; o < 256; o <<= 1) {
        int t = (tid >= o) ? sc[tid - o] : 0;
        __syncthreads();
        sc[tid] += t;
        __syncthreads();
    }
    if (tid < ncb) { baseS[tid] = sc[tid] - v; curS[tid] = sc[tid] - v; }
    if (tid == 0) { baseS[ncb] = sc[255]; rowptrS[N] = NE; }
    __syncthreads();
    v = (tid < ncb) ? histD[tid] : 0;
    sc[tid] = v;
    __syncthreads();
    for (int o = 1; o < 256; o <<= 1) {
        int t = (tid >= o) ? sc[tid - o] : 0;
        __syncthreads();
        sc[tid] += t;
        __syncthreads();
    }
    if (tid < ncb) { baseD[tid] = sc[tid] - v; curD[tid] = sc[tid] - v; }
    if (tid == 0) { baseD[ncb] = sc[255]; rowptrD[N] = NE; }
}

// chunked scatter into coarse streams, LDS-binned (full-line appends).
__global__ __launch_bounds__(256) void k_scatterC(const int* __restrict__ ei,
                                                  int* __restrict__ gcurS,
                                                  int* __restrict__ gcurD,
                                                  unsigned int* __restrict__ recS,
                                                  unsigned int* __restrict__ recD,
                                                  int E, int NE, int ncb) {
    __shared__ unsigned int srt[CHUNK];          // 16 KB
    __shared__ int cnt[NCB_MAX], off[NCB_MAX], cur[NCB_MAX], gpos[NCB_MAX], sc[256];
    const int tid = threadIdx.x;
    const int t0  = blockIdx.x * CHUNK;
    const int m   = min(CHUNK, NE - t0);

    unsigned int myrec[CHUNK / 256];
    int nmy = 0;
    for (int i = tid; i < m; i += 256) {
        int t = t0 + i;
        int src, dst;
        if (t < E) { src = ei[t]; dst = ei[E + t]; }
        else       { src = dst = t - E; }
        myrec[nmy++] = (unsigned int)src | ((unsigned int)dst << 16);
    }

    for (int side = 0; side < 2; side++) {       // 0 = S (by src), 1 = D (by dst)
        cnt[tid] = 0;
        __syncthreads();
        int mybkt[CHUNK / 256];
        for (int k = 0; k < nmy; k++) {
            unsigned int r = myrec[k];
            int node = side ? (int)(r >> 16) : (int)(r & 0xFFFFu);
            mybkt[k] = node >> CSH;
            atomicAdd(&cnt[mybkt[k]], 1);
        }
        __syncthreads();
        int v = cnt[tid];
        sc[tid] = v;
        __syncthreads();
        for (int o = 1; o < 256; o <<= 1) {
            int t = (tid >= o) ? sc[tid - o] : 0;
            __syncthreads();
            sc[tid] += t;
            __syncthreads();
        }
        off[tid] = sc[tid] - v;
        cur[tid] = sc[tid] - v;
        __syncthreads();
        for (int k = 0; k < nmy; k++) {
            int p = atomicAdd(&cur[mybkt[k]], 1);
            srt[p] = myrec[k];
        }
        __syncthreads();
        int* gcur = side ? gcurD : gcurS;
        if (tid < ncb) {
            int c = cnt[tid];
            gpos[tid] = c ? atomicAdd(&gcur[tid], c) : 0;
        }
        __syncthreads();
        unsigned int* recX = side ? recD : recS;
        for (int i = tid; i < m; i += 256) {
            unsigned int r = srt[i];
            int node = side ? (int)(r >> 16) : (int)(r & 0xFFFFu);
            int cb = node >> CSH;
            recX[gpos[cb] + (i - off[cb])] = r;
        }
        __syncthreads();
    }
}

// block per (side, coarse bucket): node-level CSR inside private region.
__global__ __launch_bounds__(256) void k_rebin(const unsigned int* __restrict__ recS,
                                               const unsigned int* __restrict__ recD,
                                               const int* __restrict__ baseS,
                                               const int* __restrict__ baseD,
                                               unsigned short* __restrict__ adjS,
                                               unsigned short* __restrict__ adjD,
                                               int* __restrict__ rowptrS,
                                               int* __restrict__ rowptrD,
                                               int ncb, int N) {
    __shared__ int cnt[256], cur[256], sc[256];
    const int tid  = threadIdx.x;
    const int side = (blockIdx.x >= ncb) ? 1 : 0;
    const int cb   = side ? blockIdx.x - ncb : blockIdx.x;
    const unsigned int* rec = side ? recD : recS;
    const int* base = side ? baseD : baseS;
    const int b0 = base[cb], b1 = base[cb + 1];
    const int tot_rec = b1 - b0;

    cnt[tid] = 0;
    __syncthreads();
    for (int i = tid; i < tot_rec; i += 256) {
        unsigned int r = rec[b0 + i];
        int node = side ? (int)(r >> 16) : (int)(r & 0xFFFFu);
        atomicAdd(&cnt[node & 255], 1);
    }
    __syncthreads();
    int v = cnt[tid];
    sc[tid] = v;
    __syncthreads();
    for (int o = 1; o < 256; o <<= 1) {
        int t = (tid >= o) ? sc[tid - o] : 0;
        __syncthreads();
        sc[tid] += t;
        __syncthreads();
    }
    int ex = sc[tid] - v;
    int node_g = (cb << CSH) + tid;
    int* rowptr = side ? rowptrD : rowptrS;
    if (node_g < N) rowptr[node_g] = b0 + ex;
    cur[tid] = ex;
    __syncthreads();
    unsigned short* adj = side ? adjD : adjS;
    for (int i = tid; i < tot_rec; i += 256) {
        unsigned int r = rec[b0 + i];
        int node = side ? (int)(r >> 16) : (int)(r & 0xFFFFu);
        unsigned short other = side ? (unsigned short)(r & 0xFFFFu)
                                    : (unsigned short)(r >> 16);
        int p = atomicAdd(&cur[node & 255], 1);
        adj[b0 + p] = other;
    }
}

// rdenom[n][h] = 1/(sum over out-edges exp(leaky(al[dst]+ar[n])) + 1e-16)
__global__ __launch_bounds__(256) void k_denom(const int* __restrict__ rowptrS,
                                               const unsigned short* __restrict__ adjS,
                                               const float* __restrict__ al,
                                               const float* __restrict__ ar,
                                               float* __restrict__ rdenom, int N) {
    int n = blockIdx.x * 256 + threadIdx.x;
    if (n >= N) return;
    int beg = rowptrS[n], end = rowptrS[n + 1];
    float4 arv = *(const float4*)(ar + n * NH);
    float s0 = 0.f, s1 = 0.f, s2 = 0.f, s3 = 0.f;
    int i = beg;
    for (; i + 2 <= end; i += 2) {
        int d0 = adjS[i], d1 = adjS[i + 1];
        float4 av0 = *(const float4*)(al + d0 * NH);
        float4 av1 = *(const float4*)(al + d1 * NH);
        float a0 = av0.x + arv.x, a1 = av0.y + arv.y;
        float a2 = av0.z + arv.z, a3 = av0.w + arv.w;
        float c0 = av1.x + arv.x, c1 = av1.y + arv.y;
        float c2 = av1.z + arv.z, c3 = av1.w + arv.w;
        a0 = (a0 > 0.f) ? a0 : NEG_SLOPE * a0;
        a1 = (a1 > 0.f) ? a1 : NEG_SLOPE * a1;
        a2 = (a2 > 0.f) ? a2 : NEG_SLOPE * a2;
        a3 = (a3 > 0.f) ? a3 : NEG_SLOPE * a3;
        c0 = (c0 > 0.f) ? c0 : NEG_SLOPE * c0;
        c1 = (c1 > 0.f) ? c1 : NEG_SLOPE * c1;
        c2 = (c2 > 0.f) ? c2 : NEG_SLOPE * c2;
        c3 = (c3 > 0.f) ? c3 : NEG_SLOPE * c3;
        s0 += __expf(a0) + __expf(c0);
        s1 += __expf(a1) + __expf(c1);
        s2 += __expf(a2) + __expf(c2);
        s3 += __expf(a3) + __expf(c3);
    }
    if (i < end) {
        int d0 = adjS[i];
        float4 av = *(const float4*)(al + d0 * NH);
        float a0 = av.x + arv.x, a1 = av.y + arv.y;
        float a2 = av.z + arv.z, a3 = av.w + arv.w;
        a0 = (a0 > 0.f) ? a0 : NEG_SLOPE * a0;
        a1 = (a1 > 0.f) ? a1 : NEG_SLOPE * a1;
        a2 = (a2 > 0.f) ? a2 : NEG_SLOPE * a2;
        a3 = (a3 > 0.f) ? a3 : NEG_SLOPE * a3;
        s0 += __expf(a0); s1 += __expf(a1);
        s2 += __expf(a2); s3 += __expf(a3);
    }
    float4 r;
    r.x = 1.0f / (s0 + 1e-16f);
    r.y = 1.0f / (s1 + 1e-16f);
    r.z = 1.0f / (s2 + 1e-16f);
    r.w = 1.0f / (s3 + 1e-16f);
    *(float4*)(rdenom + n * NH) = r;
}

// wD[i][hh] = half( exp(leaky(al[n][hh]+ar[s][hh])) * rdenom[s][hh] ),
// dst-CSR order. One thread per dst node.
__global__ __launch_bounds__(256) void k_wedge(const int* __restrict__ rowptrD,
                                               const unsigned short* __restrict__ adjD,
                                               const float* __restrict__ al,
                                               const float* __restrict__ ar,
                                               const float* __restrict__ rdenom,
                                               unsigned short* __restrict__ wD, int N) {
    int n = blockIdx.x * 256 + threadIdx.x;
    if (n >= N) return;
    int beg = rowptrD[n], end = rowptrD[n + 1];
    float4 alv = *(const float4*)(al + n * NH);
    for (int i = beg; i < end; i++) {
        int s = adjD[i];
        float4 rv = *(const float4*)(ar + s * NH);
        float4 dv = *(const float4*)(rdenom + s * NH);
        float a0 = alv.x + rv.x, a1 = alv.y + rv.y;
        float a2 = alv.z + rv.z, a3 = alv.w + rv.w;
        a0 = (a0 > 0.f) ? a0 : NEG_SLOPE * a0;
        a1 = (a1 > 0.f) ? a1 : NEG_SLOPE * a1;
        a2 = (a2 > 0.f) ? a2 : NEG_SLOPE * a2;
        a3 = (a3 > 0.f) ? a3 : NEG_SLOPE * a3;
        ushort4 w;
        w.x = __half_as_ushort(__float2half(__expf(a0) * dv.x));
        w.y = __half_as_ushort(__float2half(__expf(a1) * dv.y));
        w.z = __half_as_ushort(__float2half(__expf(a2) * dv.z));
        w.w = __half_as_ushort(__float2half(__expf(a3) * dv.w));
        *(ushort4*)(wD + (size_t)i * NH) = w;
    }
}

// agg: pure gather+FMA. 4 nodes/block, 64 threads/node, 2 ch/thread,
// 4-edge unroll for MLP.
__global__ __launch_bounds__(256) void k_agg(const int* __restrict__ rowptrD,
                                             const unsigned short* __restrict__ adjD,
                                             const unsigned short* __restrict__ wD,
                                             const unsigned short* __restrict__ h_bf,
                                             const float* __restrict__ bias,
                                             float* __restrict__ out, int N) {
    int n = blockIdx.x * 4 + (threadIdx.x >> 6);
    if (n >= N) return;
    int lane = threadIdx.x & 63;
    int c    = lane * 2;
    int hh   = lane >> 4;
    int beg = rowptrD[n], end = rowptrD[n + 1];
    float a0 = bias[c], a1 = bias[c + 1];
    float b0 = 0.f, b1 = 0.f;
    int i = beg;
    for (; i + 4 <= end; i += 4) {
        int s0 = adjD[i],     s1 = adjD[i + 1];
        int s2 = adjD[i + 2], s3 = adjD[i + 3];
        float w0 = __half2float(__ushort_as_half(wD[(size_t)i * NH + hh]));
        float w1 = __half2float(__ushort_as_half(wD[(size_t)(i + 1) * NH + hh]));
        float w2 = __half2float(__ushort_as_half(wD[(size_t)(i + 2) * NH + hh]));
        float w3 = __half2float(__ushort_as_half(wD[(size_t)(i + 3) * NH + hh]));
        ushort2 u0 = *(const ushort2*)(h_bf + (size_t)s0 * HC + c);
        ushort2 u1 = *(const ushort2*)(h_bf + (size_t)s1 * HC + c);
        ushort2 u2 = *(const ushort2*)(h_bf + (size_t)s2 * HC + c);
        ushort2 u3 = *(const ushort2*)(h_bf + (size_t)s3 * HC + c);
        a0 += bf2f(u0.x) * w0;  a1 += bf2f(u0.y) * w0;
        b0 += bf2f(u1.x) * w1;  b1 += bf2f(u1.y) * w1;
        a0 += bf2f(u2.x) * w2;  a1 += bf2f(u2.y) * w2;
        b0 += bf2f(u3.x) * w3;  b1 += bf2f(u3.y) * w3;
    }
    for (; i < end; i++) {
        int s0 = adjD[i];
        float w0 = __half2float(__ushort_as_half(wD[(size_t)i * NH + hh]));
        ushort2 u0 = *(const ushort2*)(h_bf + (size_t)s0 * HC + c);
        a0 += bf2f(u0.x) * w0;
        a1 += bf2f(u0.y) * w0;
    }
    *(float2*)(out + (size_t)n * HC + c) = make_float2(a0 + b0, a1 + b1);
}

extern "C" void kernel_launch(void* const* d_in, const int* in_sizes, int n_in,
                              void* d_out, int out_size, void* d_ws, size_t ws_size,
                              hipStream_t stream) {
    const float* x    = (const float*)d_in[0];
    const float* W    = (const float*)d_in[1];
    const float* att  = (const float*)d_in[2];
    const float* bias = (const float*)d_in[3];
    const int*   ei   = (const int*)d_in[4];

    const int N  = in_sizes[0] / IND;     // 50000
    const int E  = in_sizes[4] / 2;       // 800000
    const int NE = E + N;
    const int ncb = (N + (1 << CSH) - 1) >> CSH;   // 196
    float* out = (float*)d_out;
    const int nodeTot = N * NH;

    // ws layout
    unsigned short* h_bf  = (unsigned short*)d_ws;             // N*128 u16 = 12.8MB
    unsigned short* WT_bf = h_bf + (size_t)N * HC;             // 32K u16
    float* al      = (float*)(WT_bf + IND * HC);               // N*4 f32
    float* ar      = al + nodeTot;                             // N*4
    float* rdenom  = ar + nodeTot;                             // N*4
    unsigned int* recS = (unsigned int*)(rdenom + nodeTot);    // NE u32
    unsigned int* recD = recS + NE;                            // NE u32
    unsigned short* adjS = (unsigned short*)(recD + NE);       // NE u16
    unsigned short* adjD = adjS + NE;                          // NE u16
    unsigned short* wD   = adjD + NE + (NE & 1);               // NE*4 u16 = 6.8MB
    int* rowptrS = (int*)(wD + (size_t)NE * NH);               // N+1
    int* rowptrD = rowptrS + (N + 2);                          // N+1
    int* histS   = rowptrD + (N + 2);                          // ncb
    int* histD   = histS + NCB_MAX;                            // ncb
    int* baseS   = histD + NCB_MAX;                            // ncb+1
    int* baseD   = baseS + (NCB_MAX + 1);                      // ncb+1
    int* curS    = baseD + (NCB_MAX + 1);                      // ncb
    int* curD    = curS + NCB_MAX;                             // ncb

    k_init0<<<1, 256, 0, stream>>>(histS, histD, ncb);
    k_wprep<<<(IND * HC + 255) / 256, 256, 0, stream>>>(W, WT_bf);
    k_gemm_mfma<<<(N + 127) / 128, 256, 0, stream>>>(x, WT_bf, att, h_bf, al, ar, N);
    k_hist<<<256, 256, 0, stream>>>(ei, histS, histD, E, NE, ncb);
    k_scanC<<<1, 256, 0, stream>>>(histS, histD, baseS, baseD, curS, curD,
                                   rowptrS, rowptrD, ncb, NE, N);
    k_scatterC<<<(NE + CHUNK - 1) / CHUNK, 256, 0, stream>>>(ei, curS, curD,
                                                             recS, recD, E, NE, ncb);
    k_rebin<<<2 * ncb, 256, 0, stream>>>(recS, recD, baseS, baseD, adjS, adjD,
                                         rowptrS, rowptrD, ncb, N);
    k_denom<<<(N + 255) / 256, 256, 0, stream>>>(rowptrS, adjS, al, ar, rdenom, N);
    k_wedge<<<(N + 255) / 256, 256, 0, stream>>>(rowptrD, adjD, al, ar, rdenom, wD, N);
    k_agg<<<(N + 3) / 4, 256, 0, stream>>>(rowptrD, adjD, wD, h_bf, bias, out, N);
}